// Round 9
// baseline (554.747 us; speedup 1.0000x reference)
//
#include <hip/hip_runtime.h>
#include <math.h>

#define ACT_LRELU  0
#define ACT_SIGMAP 1
#define ACT_SQUARE 2

typedef __attribute__((ext_vector_type(8))) short v8s;
typedef __attribute__((ext_vector_type(4))) short v4s;
typedef __attribute__((ext_vector_type(16))) float f32x16;

static __device__ __forceinline__ float lrelu(float x) { return x >= 0.f ? x : 0.2f * x; }

static __device__ __forceinline__ short bf16rne(float x) {
  unsigned u = __float_as_uint(x);
  unsigned r = (u + 0x7FFFu + ((u >> 16) & 1u)) >> 16;
  return (short)r;
}
static __device__ __forceinline__ float bf16tof(short h) {
  return __uint_as_float(((unsigned)(unsigned short)h) << 16);
}
static __device__ __forceinline__ void split3(float v, short& h, short& l, short& q) {
  h = bf16rne(v); float r1 = v - bf16tof(h);
  l = bf16rne(r1); float r2 = r1 - bf16tof(l);
  q = bf16rne(r2);
}

// -------------------------------------------------------------------------
// prep_acts: x[b][128][64] -> xm3[pl][b][t][ci], 3 bf16 planes (~exact fp32)
// -------------------------------------------------------------------------
__global__ void __launch_bounds__(256) prep_acts(
    const float* __restrict__ x, short* __restrict__ xm3)
{
  int e = blockIdx.x * 256 + threadIdx.x;
  if (e >= 131072) return;
  int b = e >> 13, rem = e & 8191, t = rem >> 7, ci = rem & 127;
  float v = x[((size_t)(b * 128) + ci) * 64 + t];
  short h, l, q; split3(v, h, l, q);
  size_t o = ((size_t)(b * 64) + t) * 128 + ci;
  xm3[0 * 131072 + o] = h;
  xm3[1 * 131072 + o] = l;
  xm3[2 * 131072 + o] = q;
}

// -------------------------------------------------------------------------
// prep_panels: all 5 m/g layers, both paths. W[Cout][Cin][3] ->
// P[pl][co][tap*Cin+ci] (3 bf16 planes, tap-major K).
// -------------------------------------------------------------------------
__global__ void __launch_bounds__(256) prep_panels(
    const float* mw0, const float* mw1, const float* mw2, const float* mw3, const float* fw,
    const float* gw0, const float* gw1, const float* gw2, const float* gw3, const float* lw,
    short* __restrict__ mP, short* __restrict__ gP)
{
  int i = blockIdx.x * 256 + threadIdx.x;
  const int PER_PATH = 917504;
  if (i >= 2 * PER_PATH) return;
  int path = i >= PER_PATH ? 1 : 0;
  int r = i - path * PER_PATH;
  int layer, Cin, Cout; size_t poff;
  if (r < 65536)       { layer = 0;               Cin = 128; Cout = 512; poff = 0; }
  else if (r < 327680) { layer = 1; r -= 65536;   Cin = 512; Cout = 512; poff = 589824; }
  else if (r < 589824) { layer = 2; r -= 327680;  Cin = 512; Cout = 512; poff = 2949120; }
  else if (r < 851968) { layer = 3; r -= 589824;  Cin = 512; Cout = 512; poff = 5308416; }
  else                 { layer = 4; r -= 851968;  Cin = 512; Cout = 128; poff = 7667712; }
  const float* Wm[5] = {mw0, mw1, mw2, mw3, fw};
  const float* Wg[5] = {gw0, gw1, gw2, gw3, lw};
  const float* W = path ? Wg[layer] : Wm[layer];
  short* P = (path ? gP : mP) + poff;
  int co = r / Cin, ci = r - co * Cin;
  const int K3 = 3 * Cin;
  const float* wp = W + (size_t)(co * Cin + ci) * 3;
#pragma unroll
  for (int tap = 0; tap < 3; ++tap) {
    short h, l, q; split3(wp[tap], h, l, q);
    size_t base = (size_t)co * K3 + tap * Cin + ci;
    P[(size_t)0 * Cout * K3 + base] = h;
    P[(size_t)1 * Cout * K3 + base] = l;
    P[(size_t)2 * Cout * K3 + base] = q;
  }
}

// -------------------------------------------------------------------------
// m/g path conv, tap-split: each block computes ONE tap's partial GEMM
// (f32) for a 64x64 tile. 2 waves (wave tile 32x64), BK=32, T14 staging.
// m path: 6 products (hh,hl,lh,ll,hq,qh ~ fp32); g path: 3 (hh,hl,lh).
// partial[(tap*2+path)*1024 + gn][co], gn = b*64+t.
// -------------------------------------------------------------------------
__global__ void __launch_bounds__(128, 2) conv_path_tap(
    const short* __restrict__ actM, const short* __restrict__ actG,
    const short* __restrict__ Pm, const short* __restrict__ Pg,
    float* __restrict__ partial, int Cin, int Cout, int psIn)
{
  const int mtiles = Cout >> 6;
  const int nblk = 2 * mtiles * 16 * 3;
  const int Q = nblk >> 3;
  int d = blockIdx.x;
  int idx = (d & 7) * Q + (d >> 3);
  int mt = idx % mtiles; int r = idx / mtiles;
  int nt = r & 15; r >>= 4;
  int tap = r % 3; int path = r / 3;

  const short* act = path ? actG : actM;
  const short* P   = path ? Pg : Pm;
  const int K3 = 3 * Cin;
  const int co0 = mt * 64;
  const int NT  = Cin >> 5;
  const int npl = path ? 2 : 3;

  const int tid = threadIdx.x;
  const int w = tid >> 6;          // wm: 0..1
  const int l = tid & 63;

  __shared__ __align__(16) short Al[3][64 * 40];
  __shared__ __align__(16) short Bl[3][64 * 40];

  f32x16 acc[2] = {};
  v8s rA[3][2], rB[3][2];

  auto LOADA = [&](int t) {
    int ci0 = t << 5;
#pragma unroll
    for (int pl = 0; pl < 3; ++pl) {
      if (pl >= npl) break;
#pragma unroll
      for (int it = 0; it < 2; ++it) {
        int e = it * 128 + tid;
        int row = e >> 2, c8 = e & 3;
        rA[pl][it] = *(const v8s*)&P[(size_t)pl * Cout * K3 + (size_t)(co0 + row) * K3
                                     + tap * Cin + ci0 + c8 * 8];
      }
    }
  };
  auto LOADB = [&](int t) {
    int ci0 = t << 5;
#pragma unroll
    for (int pl = 0; pl < 3; ++pl) {
      if (pl >= npl) break;
#pragma unroll
      for (int it = 0; it < 2; ++it) {
        int e = it * 128 + tid;
        int n = e >> 2, c8 = e & 3;
        int trow = n + tap - 1;                    // t within batch nt
        v8s vv = {};
        if (trow >= 0 && trow < 64)
          vv = *(const v8s*)&act[(size_t)pl * psIn + ((size_t)(nt * 64 + trow)) * Cin
                                 + ci0 + c8 * 8];
        rB[pl][it] = vv;
      }
    }
  };
  auto WRITE = [&]() {
#pragma unroll
    for (int pl = 0; pl < 3; ++pl) {
      if (pl >= npl) break;
#pragma unroll
      for (int it = 0; it < 2; ++it) {
        int e = it * 128 + tid;
        *(v8s*)&Al[pl][(e >> 2) * 40 + (e & 3) * 8] = rA[pl][it];
        *(v8s*)&Bl[pl][(e >> 2) * 40 + (e & 3) * 8] = rB[pl][it];
      }
    }
  };

  LOADA(0); LOADB(0);
  WRITE();
  __syncthreads();

  for (int t = 0; t < NT; ++t) {
    if (t + 1 < NT) { LOADA(t + 1); LOADB(t + 1); }
    const int lr = l & 31, lh = (l >> 5) * 8;
#pragma unroll
    for (int kk = 0; kk < 2; ++kk) {
      const int ao = (w * 32 + lr) * 40 + kk * 16 + lh;
      v8s a0 = *(const v8s*)&Al[0][ao];
      v8s a1 = *(const v8s*)&Al[1][ao];
#pragma unroll
      for (int fn = 0; fn < 2; ++fn) {
        const int bo = (fn * 32 + lr) * 40 + kk * 16 + lh;
        v8s b0 = *(const v8s*)&Bl[0][bo];
        v8s b1 = *(const v8s*)&Bl[1][bo];
        acc[fn] = __builtin_amdgcn_mfma_f32_32x32x16_bf16(a0, b0, acc[fn], 0, 0, 0);
        acc[fn] = __builtin_amdgcn_mfma_f32_32x32x16_bf16(a0, b1, acc[fn], 0, 0, 0);
        acc[fn] = __builtin_amdgcn_mfma_f32_32x32x16_bf16(a1, b0, acc[fn], 0, 0, 0);
        if (path == 0) {
          v8s a2 = *(const v8s*)&Al[2][ao];
          v8s b2 = *(const v8s*)&Bl[2][bo];
          acc[fn] = __builtin_amdgcn_mfma_f32_32x32x16_bf16(a1, b1, acc[fn], 0, 0, 0);
          acc[fn] = __builtin_amdgcn_mfma_f32_32x32x16_bf16(a0, b2, acc[fn], 0, 0, 0);
          acc[fn] = __builtin_amdgcn_mfma_f32_32x32x16_bf16(a2, b0, acc[fn], 0, 0, 0);
        }
      }
    }
    __syncthreads();
    if (t + 1 < NT) { WRITE(); __syncthreads(); }
  }

  // epilogue: partial f32. C/D: col=lane&31, row=(r&3)+8*(r>>2)+4*(lane>>5)
  const int hi4 = 4 * (l >> 5);
  const size_t pbase = (size_t)(tap * 2 + path) * 1024;
#pragma unroll
  for (int fn = 0; fn < 2; ++fn) {
    int gn = nt * 64 + fn * 32 + (l & 31);
#pragma unroll
    for (int q4 = 0; q4 < 4; ++q4) {
      int co = co0 + w * 32 + q4 * 8 + hi4;
      float4 v = {acc[fn][q4 * 4 + 0], acc[fn][q4 * 4 + 1],
                  acc[fn][q4 * 4 + 2], acc[fn][q4 * 4 + 3]};
      *(float4*)&partial[(pbase + gn) * Cout + co] = v;
    }
  }
}

// -------------------------------------------------------------------------
// finalize (LRELU layers): sum 3 tap partials + bias, lrelu, split3 ->
// 3-plane bf16 activations [pl][b][t][512].
// -------------------------------------------------------------------------
__global__ void __launch_bounds__(256) finalize_lrelu(
    const float* __restrict__ partial,
    const float* __restrict__ BsM, const float* __restrict__ BsG,
    short* __restrict__ soutM, short* __restrict__ soutG)
{
  int e = blockIdx.x * 256 + threadIdx.x;   // < 262144
  int c4 = e & 127, gn = (e >> 7) & 1023, path = e >> 17;
  const float* Bs = path ? BsG : BsM;
  short* sout = path ? soutG : soutM;
  size_t base = ((size_t)(path) * 1024 + gn) * 512 + c4 * 4;
  const size_t TS = (size_t)2 * 1024 * 512;
  float4 s0 = *(const float4*)&partial[base];
  float4 s1 = *(const float4*)&partial[base + TS];
  float4 s2 = *(const float4*)&partial[base + 2 * TS];
  float4 bi = *(const float4*)&Bs[c4 * 4];
  const float* p0 = &s0.x; const float* p1 = &s1.x;
  const float* p2 = &s2.x; const float* pb = &bi.x;
  v4s h4, l4, q4v;
#pragma unroll
  for (int j = 0; j < 4; ++j) {
    float z = lrelu(p0[j] + p1[j] + p2[j] + pb[j]);
    short h, lo, qq; split3(z, h, lo, qq);
    h4[j] = h; l4[j] = lo; q4v[j] = qq;
  }
  size_t o = (size_t)gn * 512 + c4 * 4;
  *(v4s*)&sout[0 * 524288 + o] = h4;
  *(v4s*)&sout[1 * 524288 + o] = l4;
  *(v4s*)&sout[2 * 524288 + o] = q4v;
}

// -------------------------------------------------------------------------
// finalize (layer 5): m -> SIGMAP band map into fsm[b][co][t];
//                     g -> squared into lsm[b][co][t].  Cout=128.
// -------------------------------------------------------------------------
__global__ void __launch_bounds__(256) finalize_l5(
    const float* __restrict__ partial,
    const float* __restrict__ fb, const float* __restrict__ lb,
    float* __restrict__ fsm, float* __restrict__ lsm)
{
  __shared__ float bandS[2][128];
  int tid = threadIdx.x;
  if (tid < 128) {
    double lg = log(551.25);
    double stop  = 20.0 * exp(lg * (double)tid / 127.0);
    double start = (tid == 0) ? 0.0 : 20.0 * exp(lg * (double)(tid - 1) / 127.0);
    bandS[0][tid] = (float)start;
    bandS[1][tid] = (float)(stop - start);
  }
  __syncthreads();

  int e = blockIdx.x * 256 + tid;   // < 65536
  int c4 = e & 31, gn = (e >> 5) & 1023, path = e >> 15;
  size_t base = ((size_t)(path) * 1024 + gn) * 128 + c4 * 4;
  const size_t TS = (size_t)2 * 1024 * 128;
  float4 s0 = *(const float4*)&partial[base];
  float4 s1 = *(const float4*)&partial[base + TS];
  float4 s2 = *(const float4*)&partial[base + 2 * TS];
  float4 bi = *(const float4*)&((path ? lb : fb)[c4 * 4]);
  const float* p0 = &s0.x; const float* p1 = &s1.x;
  const float* p2 = &s2.x; const float* pb = &bi.x;
  int b = gn >> 6, t = gn & 63;
#pragma unroll
  for (int j = 0; j < 4; ++j) {
    int co = c4 * 4 + j;
    float z = p0[j] + p1[j] + p2[j] + pb[j];
    if (path == 0)
      fsm[((size_t)(b * 128) + co) * 64 + t] = bandS[0][co] + bandS[1][co] / (1.f + expf(-z));
    else
      lsm[((size_t)(b * 128) + co) * 64 + t] = z * z;
  }
}

// -------------------------------------------------------------------------
// fold_all: 4 noise layers (k=7+nearest-x2 -> 4-tap parity, hi/lo bf16,
// tap-major) + nl panel (17->32 padded, k=3, hi/lo, tap-major K=1536).
// -------------------------------------------------------------------------
__global__ void __launch_bounds__(256) fold_all(
    const float* __restrict__ nw0, const float* __restrict__ nw1,
    const float* __restrict__ nw2, const float* __restrict__ nw3,
    const float* __restrict__ nlw,
    short* __restrict__ E1, short* __restrict__ E2,
    short* __restrict__ E3, short* __restrict__ E4,
    short* __restrict__ Pnl)
{
  int i = blockIdx.x * 256 + threadIdx.x;
  if (i >= 851968) {
    if (i >= 868352) return;
    int idx = i - 851968;             // [0, 32*512)
    int co = idx >> 9, ci = idx & 511;
#pragma unroll
    for (int tap = 0; tap < 3; ++tap) {
      float v = (co < 17) ? nlw[((size_t)(co * 512 + ci)) * 3 + tap] : 0.f;
      short h = bf16rne(v);
      short lo = bf16rne(v - bf16tof(h));
      Pnl[(size_t)(0 * 32 + co) * 1536 + tap * 512 + ci] = h;
      Pnl[(size_t)(1 * 32 + co) * 1536 + tap * 512 + ci] = lo;
    }
    return;
  }
  const float* W; short* Ag; int Cin; int idx;
  if (i < 65536)        { W = nw0; Ag = E1; Cin = 128; idx = i; }
  else if (i < 327680)  { W = nw1; Ag = E2; Cin = 512; idx = i - 65536; }
  else if (i < 589824)  { W = nw2; Ag = E3; Cin = 512; idx = i - 327680; }
  else                  { W = nw3; Ag = E4; Cin = 512; idx = i - 589824; }
  int co = idx / Cin, ci = idx - co * Cin;
  const float* wp = W + (size_t)idx * 7;
  float f[2][4] = {{wp[0],         wp[1] + wp[2], wp[3] + wp[4], wp[5] + wp[6]},
                   {wp[0] + wp[1], wp[2] + wp[3], wp[4] + wp[5], wp[6]}};
  const int K = Cin * 4;
#pragma unroll
  for (int par = 0; par < 2; ++par)
#pragma unroll
    for (int q = 0; q < 4; ++q) {
      float v = f[par][q];
      short h = bf16rne(v);
      short lo = bf16rne(v - bf16tof(h));
      Ag[((size_t)((par * 2 + 0) * 512 + co)) * K + q * Cin + ci] = h;
      Ag[((size_t)((par * 2 + 1) * 512 + co)) * K + q * Cin + ci] = lo;
    }
}

// -------------------------------------------------------------------------
// Noise conv: 2-plane split-bf16 MFMA GEMM (hh,hl,lh), 32x32x16, T14 async.
// Always writes 2-plane bf16 [pl][b][t][512] for the next consumer.
// -------------------------------------------------------------------------
template<int MF, int BNS, int CIN>
__global__ void __launch_bounds__(256, 2) conv_noise(
    const short* __restrict__ actIn, const short* __restrict__ Ag,
    const float* __restrict__ Bs, short* __restrict__ actOut,
    int Sin, int psIn, int psOut)
{
  constexpr int NF   = BNS / 64;
  constexpr int BM   = MF * 64;
  constexpr int AITS = BM / 32;
  constexpr int BITS = BNS / 32;
  constexpr int K    = CIN * 4;
  constexpr int nci  = CIN / 64;
  constexpr int NT   = 4 * nci;
  const int mtiles = 512 / BM;
  const int stiles = Sin / BNS;
  const int nblk = mtiles * 2 * 16 * stiles;
  const int Q = nblk >> 3;
  int d = blockIdx.x;
  int idx = (d & 7) * Q + (d >> 3);
  int mt = idx % mtiles;
  int t1 = idx / mtiles;
  int par = t1 & 1;
  int rest = t1 >> 1;
  int st = rest % stiles;
  int b = rest / stiles;

  const int co0 = mt * BM;
  const int s0 = st * BNS;
  const int soff = par ? -1 : -2;

  const int tid = threadIdx.x;
  const int w = tid >> 6, wm = w & 1, wn = w >> 1;
  const int l = tid & 63;

  __shared__ __align__(16) short Al[2][BM * 72];
  __shared__ __align__(16) short Bl[2][BNS * 72];

  f32x16 acc[MF][NF] = {};
  v8s rA[2][AITS], rB[2][BITS];

  auto LOADA = [&](int t) {
    int q = t / nci, ci0 = (t % nci) << 6;
#pragma unroll
    for (int pl = 0; pl < 2; ++pl)
#pragma unroll
      for (int it = 0; it < AITS; ++it) {
        int e = it * 256 + tid;
        int row = e >> 3, c8 = e & 7;
        rA[pl][it] = *(const v8s*)&Ag[((size_t)((par * 2 + pl) * 512 + co0 + row)) * K
                                      + q * CIN + ci0 + c8 * 8];
      }
  };
  auto LOADB = [&](int t) {
    int q = t / nci, ci0 = (t % nci) << 6;
#pragma unroll
    for (int pl = 0; pl < 2; ++pl)
#pragma unroll
      for (int it = 0; it < BITS; ++it) {
        int e = it * 256 + tid;
        int n = e >> 3, c8 = e & 7;
        int srow = s0 + n + q + soff;
        v8s vv = {};
        if (srow >= 0 && srow < Sin)
          vv = *(const v8s*)&actIn[(size_t)pl * psIn + ((size_t)(b * Sin + srow)) * CIN
                                   + ci0 + c8 * 8];
        rB[pl][it] = vv;
      }
  };
  auto WRITE = [&]() {
#pragma unroll
    for (int pl = 0; pl < 2; ++pl) {
#pragma unroll
      for (int it = 0; it < AITS; ++it) {
        int e = it * 256 + tid;
        *(v8s*)&Al[pl][(e >> 3) * 72 + (e & 7) * 8] = rA[pl][it];
      }
#pragma unroll
      for (int it = 0; it < BITS; ++it) {
        int e = it * 256 + tid;
        *(v8s*)&Bl[pl][(e >> 3) * 72 + (e & 7) * 8] = rB[pl][it];
      }
    }
  };

  LOADA(0); LOADB(0);
  WRITE();
  __syncthreads();

  for (int t = 0; t < NT; ++t) {
    if (t + 1 < NT) { LOADA(t + 1); LOADB(t + 1); }
    const int lr = l & 31, lh = (l >> 5) * 8;
#pragma unroll
    for (int kk = 0; kk < 4; ++kk) {
      v8s ah[MF], al[MF], bh[NF], bl[NF];
#pragma unroll
      for (int fm = 0; fm < MF; ++fm) {
        int ab = (wm * (MF * 32) + fm * 32 + lr) * 72 + kk * 16 + lh;
        ah[fm] = *(const v8s*)&Al[0][ab];
        al[fm] = *(const v8s*)&Al[1][ab];
      }
#pragma unroll
      for (int fn = 0; fn < NF; ++fn) {
        int bb = (wn * (BNS / 2) + fn * 32 + lr) * 72 + kk * 16 + lh;
        bh[fn] = *(const v8s*)&Bl[0][bb];
        bl[fn] = *(const v8s*)&Bl[1][bb];
      }
#pragma unroll
      for (int fm = 0; fm < MF; ++fm)
#pragma unroll
        for (int fn = 0; fn < NF; ++fn) {
          acc[fm][fn] = __builtin_amdgcn_mfma_f32_32x32x16_bf16(ah[fm], bh[fn], acc[fm][fn], 0, 0, 0);
          acc[fm][fn] = __builtin_amdgcn_mfma_f32_32x32x16_bf16(ah[fm], bl[fn], acc[fm][fn], 0, 0, 0);
          acc[fm][fn] = __builtin_amdgcn_mfma_f32_32x32x16_bf16(al[fm], bh[fn], acc[fm][fn], 0, 0, 0);
        }
    }
    __syncthreads();
    if (t + 1 < NT) { WRITE(); __syncthreads(); }
  }

  // epilogue: always 2-plane bf16 [pl][b][t=2s+par][512]
  const int hi4 = 4 * (l >> 5);
  const int T2 = 2 * Sin;
#pragma unroll
  for (int fm = 0; fm < MF; ++fm)
#pragma unroll
    for (int q4 = 0; q4 < 4; ++q4) {
      int co = co0 + wm * (MF * 32) + fm * 32 + q4 * 8 + hi4;
      float4 bia = *(const float4*)&Bs[co];
      const float* bp = &bia.x;
#pragma unroll
      for (int fn = 0; fn < NF; ++fn) {
        int s_l = wn * (BNS / 2) + fn * 32 + (l & 31);
        int t = 2 * (s0 + s_l) + par;
        v4s h4, l4;
#pragma unroll
        for (int j = 0; j < 4; ++j) {
          float z = lrelu(acc[fm][fn][q4 * 4 + j] + bp[j]);
          short h = bf16rne(z);
          h4[j] = h;
          l4[j] = bf16rne(z - bf16tof(h));
        }
        size_t o = ((size_t)(b * T2) + t) * 512 + co;
        *(v4s*)&actOut[0 * (size_t)psOut + o] = h4;
        *(v4s*)&actOut[1 * (size_t)psOut + o] = l4;
      }
    }
}

// -------------------------------------------------------------------------
// conv_nl as split-bf16 MFMA GEMM: M=32 (17 padded), K=3*512 via shifted-row
// LDS taps, N=16x1024. BN=64, 2 waves, grid 256. Output squared.
// -------------------------------------------------------------------------
#define NL_PS4 8388608   // l4act plane stride (shorts)

__global__ void __launch_bounds__(128) conv_nl_mfma(
    const short* __restrict__ act, const short* __restrict__ Pnl,
    const float* __restrict__ Bs, float* __restrict__ outNl)
{
  const int bid = blockIdx.x;
  const int b = bid >> 4, t0 = (bid & 15) << 6;
  const int tid = threadIdx.x;
  const int w = tid >> 6;        // 0..1
  const int l = tid & 63;

  __shared__ __align__(16) short Al[2 * 3 * 32 * 72];
  __shared__ __align__(16) short Bl[2 * 66 * 72];

  f32x16 acc = {};

  for (int ci0 = 0; ci0 < 512; ci0 += 64) {
    for (int e = tid; e < 1536; e += 128) {
      int c8 = e & 7, row = e >> 3;
      int pl = row >= 96;
      int r2 = row - pl * 96;
      int tap = r2 >> 5, co = r2 & 31;
      v8s vv = *(const v8s*)&Pnl[(size_t)(pl * 32 + co) * 1536 + tap * 512 + ci0 + c8 * 8];
      *(v8s*)&Al[row * 72 + c8 * 8] = vv;
    }
    for (int e = tid; e < 1056; e += 128) {
      int c8 = e & 7, r = (e >> 3) % 66, pl = (e >> 3) / 66;
      int t = t0 + r - 1;
      v8s vv = {};
      if (t >= 0 && t < 1024)
        vv = *(const v8s*)&act[(size_t)pl * NL_PS4 + ((size_t)(b << 10) + t) * 512 + ci0 + c8 * 8];
      *(v8s*)&Bl[(pl * 66 + r) * 72 + c8 * 8] = vv;
    }
    __syncthreads();
    const int lr = l & 31, lh = (l >> 5) * 8;
#pragma unroll
    for (int kk = 0; kk < 4; ++kk)
#pragma unroll
      for (int tap = 0; tap < 3; ++tap) {
        v8s a_h = *(const v8s*)&Al[((0 * 3 + tap) * 32 + lr) * 72 + kk * 16 + lh];
        v8s a_l = *(const v8s*)&Al[((1 * 3 + tap) * 32 + lr) * 72 + kk * 16 + lh];
        int brow = w * 32 + lr + tap;
        v8s b_h = *(const v8s*)&Bl[(0 * 66 + brow) * 72 + kk * 16 + lh];
        v8s b_l = *(const v8s*)&Bl[(1 * 66 + brow) * 72 + kk * 16 + lh];
        acc = __builtin_amdgcn_mfma_f32_32x32x16_bf16(a_h, b_h, acc, 0, 0, 0);
        acc = __builtin_amdgcn_mfma_f32_32x32x16_bf16(a_h, b_l, acc, 0, 0, 0);
        acc = __builtin_amdgcn_mfma_f32_32x32x16_bf16(a_l, b_h, acc, 0, 0, 0);
      }
    __syncthreads();
  }

  const int t = t0 + w * 32 + (l & 31);
  const int hi4 = 4 * (l >> 5);
#pragma unroll
  for (int q4 = 0; q4 < 4; ++q4) {
#pragma unroll
    for (int j = 0; j < 4; ++j) {
      int co = q4 * 8 + hi4 + j;
      if (co < 17) {
        float z = acc[q4 * 4 + j] + Bs[co];
        outNl[((size_t)(b * 17) + co) * 1024 + t] = z * z;
      }
    }
  }
}

// -------------------------------------------------------------------------
// Noise bank: per 32-sample frame, 17-bin real DFT * mags, inverse, store.
// -------------------------------------------------------------------------
__global__ void __launch_bounds__(64) noise_filter(
    const float* __restrict__ noise, const float* __restrict__ mags,
    float* __restrict__ filt)
{
  __shared__ float ct[32], st[32];
  int tid = threadIdx.x;
  if (tid < 32) {
    double a = (double)tid * (3.14159265358979323846 / 16.0);
    ct[tid] = (float)cos(a);
    st[tid] = (float)sin(a);
  }
  __syncthreads();

  int fidx = blockIdx.x * 64 + tid;
  int b = fidx >> 10, i = fidx & 1023;

  float xv[32];
#pragma unroll
  for (int n = 0; n < 32; ++n) {
    int idx = i * 16 + n;
    xv[n] = (idx < 16384) ? noise[(size_t)b * 16384 + idx] : 0.f;
  }

  float Yr[17], Yi[17];
#pragma unroll
  for (int k = 0; k <= 16; ++k) {
    float xr = 0.f, xi = 0.f;
    int kk = 0;
#pragma unroll
    for (int n = 0; n < 32; ++n) {
      xr += xv[n] * ct[kk];
      xi -= xv[n] * st[kk];
      kk = (kk + k) & 31;
    }
    float m = mags[((size_t)b * 17 + k) * 1024 + i];
    Yr[k] = xr * m;
    Yi[k] = xi * m;
  }

  float* fo = filt + ((size_t)b * 1024 + i) * 32;
#pragma unroll
  for (int n = 0; n < 32; ++n) {
    float v = Yr[0] + ((n & 1) ? -Yr[16] : Yr[16]);
    int kk = n;
#pragma unroll
    for (int k = 1; k <= 15; ++k) {
      v += 2.f * (Yr[k] * ct[kk] - Yi[k] * st[kk]);
      kk = (kk + n) & 31;
    }
    fo[n] = v * (1.f / 32.f);
  }
}

// -------------------------------------------------------------------------
// Oscillator bank (3-point lerp endpoints + f64 chunk base + f32 Kahan).
// -------------------------------------------------------------------------
static __device__ __forceinline__ int clamp64(int i) { return i < 0 ? 0 : (i > 63 ? 63 : i); }

__global__ void __launch_bounds__(256) osc_phase(
    const float* __restrict__ fsm, double* __restrict__ phaseBase)
{
  const int o = blockIdx.x, b = blockIdx.y;
  const float* frow = fsm + (size_t)(b * 128 + o) * 64;
  const int c = threadIdx.x;

  const float ic0 = ((float)(c * 64) - 127.5f) * (1.0f / 256.0f);
  const int ilo = (int)floorf(ic0);
  float f0 = frow[clamp64(ilo)], f1 = frow[clamp64(ilo + 1)], f2 = frow[clamp64(ilo + 2)];

  double local = 0.0;
#pragma unroll 8
  for (int j = 0; j < 64; ++j) {
    float ic = ic0 + (float)j * (1.0f / 256.0f);
    float fl = floorf(ic);
    float w  = ic - fl;
    bool hi = ((int)fl) > ilo;
    float fa = hi ? f1 : f0;
    float fb = hi ? f2 : f1;
    float f = fa * (1.f - w) + fb * w;
    f = fminf(fmaxf(f, 20.f), 11025.f);
    local += (double)f;
  }
  local *= (1.0 / 22050.0);

  __shared__ double ps[256];
  ps[c] = local;
  __syncthreads();
  for (int off = 1; off < 256; off <<= 1) {
    double v = (c >= off) ? ps[c - off] : 0.0;
    __syncthreads();
    ps[c] += v;
    __syncthreads();
  }
  phaseBase[(size_t)(b * 128 + o) * 256 + c] = ps[c] - local;
}

__global__ void __launch_bounds__(128) osc_sum(
    const float* __restrict__ fsm, const float* __restrict__ lsm,
    const double* __restrict__ phaseBase, const float* __restrict__ filt,
    float* __restrict__ out)
{
  const int c = blockIdx.x, b = blockIdx.y;
  const int tid = threadIdx.x;
  __shared__ float contrib[128][65];
  __shared__ float part[2][64];
  const int o = tid;
  const float* frow = fsm + (size_t)(b * 128 + o) * 64;
  const float* arow = lsm + (size_t)(b * 128 + o) * 64;

  double pb = phaseBase[(size_t)(b * 128 + o) * 256 + c];
  float fb0 = (float)(pb - floor(pb));

  const float ic0 = ((float)(c * 64) - 127.5f) * (1.0f / 256.0f);
  const int ilo = (int)floorf(ic0);
  float f0 = frow[clamp64(ilo)], f1 = frow[clamp64(ilo + 1)], f2 = frow[clamp64(ilo + 2)];
  float a0 = arow[clamp64(ilo)], a1 = arow[clamp64(ilo + 1)], a2 = arow[clamp64(ilo + 2)];

  float rel = 0.f, comp = 0.f;
#pragma unroll 8
  for (int j = 0; j < 64; ++j) {
    float ic = ic0 + (float)j * (1.0f / 256.0f);
    float fl = floorf(ic);
    float w  = ic - fl;
    bool hi = ((int)fl) > ilo;
    float fa = hi ? f1 : f0;
    float fb = hi ? f2 : f1;
    float f = fa * (1.f - w) + fb * w;
    f = fminf(fmaxf(f, 20.f), 11025.f);
    float y = f * (1.0f / 22050.0f) - comp;
    float t = rel + y;
    comp = (t - rel) - y;
    rel = t;
    float tot = fb0 + rel;
    float frac = tot - floorf(tot);
    float s = sinpif(2.f * frac);
    float aa = hi ? a1 : a0;
    float ab = hi ? a2 : a1;
    float am = aa * (1.f - w) + ab * w;
    contrib[o][j] = s * am;
  }
  __syncthreads();
  int half = tid >> 6, tl = tid & 63;
  float sum = 0.f;
  for (int oo = 0; oo < 64; ++oo) sum += contrib[half * 64 + oo][tl];
  part[half][tl] = sum;
  __syncthreads();
  if (tid < 64) {
    int t = c * 64 + tid;
    float v = part[0][tid] + part[1][tid];
    int i0 = t >> 4, r = t & 15;
    v += filt[((size_t)(b << 10) + i0) * 32 + r];
    if (i0 > 0) v += filt[((size_t)(b << 10) + i0 - 1) * 32 + 16 + r];
    out[(size_t)b * 16384 + t] = v;
  }
}

// -------------------------------------------------------------------------
extern "C" void kernel_launch(void* const* d_in, const int* in_sizes, int n_in,
                              void* d_out, int out_size, void* d_ws, size_t ws_size,
                              hipStream_t stream)
{
  (void)in_sizes; (void)n_in; (void)out_size; (void)ws_size;

  const float* x     = (const float*)d_in[0];
  const float* noise = (const float*)d_in[1];
  const float* mw0 = (const float*)d_in[2];  const float* mb0 = (const float*)d_in[3];
  const float* mw1 = (const float*)d_in[4];  const float* mb1 = (const float*)d_in[5];
  const float* mw2 = (const float*)d_in[6];  const float* mb2 = (const float*)d_in[7];
  const float* mw3 = (const float*)d_in[8];  const float* mb3 = (const float*)d_in[9];
  const float* fw  = (const float*)d_in[10]; const float* fb  = (const float*)d_in[11];
  const float* gw0 = (const float*)d_in[12]; const float* gb0 = (const float*)d_in[13];
  const float* gw1 = (const float*)d_in[14]; const float* gb1 = (const float*)d_in[15];
  const float* gw2 = (const float*)d_in[16]; const float* gb2 = (const float*)d_in[17];
  const float* gw3 = (const float*)d_in[18]; const float* gb3 = (const float*)d_in[19];
  const float* lw  = (const float*)d_in[20]; const float* lb  = (const float*)d_in[21];
  const float* nw0 = (const float*)d_in[22]; const float* nb0 = (const float*)d_in[23];
  const float* nw1 = (const float*)d_in[24]; const float* nb1 = (const float*)d_in[25];
  const float* nw2 = (const float*)d_in[26]; const float* nb2 = (const float*)d_in[27];
  const float* nw3 = (const float*)d_in[28]; const float* nb3 = (const float*)d_in[29];
  const float* nlw = (const float*)d_in[30]; const float* nlb = (const float*)d_in[31];

  // ---- workspace (BYTE offsets; high-water 60,751,872 B < 63 MB cap) ----
  //  phase A: mP[0,16.5M) gP[16.5,33.0M) hm0/hm1/hg0/hg1[33.03,45.61M)
  //           partial[45.61,58.2M)  xm3[58.72,59.51M)
  //           fsm[59.51,60.03M) lsm[60.03,60.56M) Pnl[60.56,60.75M)
  //  phase N: E4[0,8.39M) E3[33.55,41.94M) E2[41.94,50.33M) E1[50.33,52.43M)
  //           l1out[52.43,56.62M) l2out[25.17,33.55M) l3out[8.39,25.17M)
  //           l4act[25.17,58.72M)
  //  tail: nl[0,1.11M) filt[1.11,3.21M) phaseBase[4.19,8.39M)
  char* W8 = (char*)d_ws;
  short* mP  = (short*)(W8 + 0);
  short* gP  = (short*)(W8 + 16515072);
  short* hm0 = (short*)(W8 + 33030144);
  short* hm1 = (short*)(W8 + 36175872);
  short* hg0 = (short*)(W8 + 39321600);
  short* hg1 = (short*)(W8 + 42467328);
  float* partial = (float*)(W8 + 45613056);  // 12,582,912 B
  short* xm3 = (short*)(W8 + 58720256);
  float* fsm = (float*)(W8 + 59506688);
  float* lsm = (float*)(W8 + 60030976);
  short* Pnl = (short*)(W8 + 60555264);    // 196,608 B

  short* E4  = (short*)(W8 + 0);           // 8,388,608 B
  short* E3  = (short*)(W8 + 33554432);    // 8,388,608 B
  short* E2  = (short*)(W8 + 41943040);    // 8,388,608 B
  short* E1  = (short*)(W8 + 50331648);    // 2,097,152 B
  short* l1out = (short*)(W8 + 52428800);  // 4,194,304 B
  short* l2out = (short*)(W8 + 25165824);  // 8,388,608 B
  short* l3out = (short*)(W8 + 8388608);   // 16,777,216 B
  short* l4act = (short*)(W8 + 25165824);  // 33,554,432 B

  float* nl   = (float*)(W8 + 0);          // 1,114,112 B
  float* filt = (float*)(W8 + 1114112);    // 2,097,152 B
  double* phaseBase = (double*)(W8 + 4194304);  // 4,194,304 B

  float* out = (float*)d_out;

  const int PS_X = 131072;   // xm3 plane stride (shorts)
  const int PS_H = 524288;   // m/g act plane stride (shorts)

  // ---- prep ----
  prep_acts<<<512, 256, 0, stream>>>(x, xm3);
  prep_panels<<<7168, 256, 0, stream>>>(mw0, mw1, mw2, mw3, fw,
                                        gw0, gw1, gw2, gw3, lw, mP, gP);

  // ---- m/g paths: tap-split MFMA + finalize ----
  conv_path_tap<<<768, 128, 0, stream>>>(xm3, xm3, mP + 0, gP + 0, partial, 128, 512, PS_X);
  finalize_lrelu<<<1024, 256, 0, stream>>>(partial, mb0, gb0, hm0, hg0);
  conv_path_tap<<<768, 128, 0, stream>>>(hm0, hg0, mP + 589824, gP + 589824, partial, 512, 512, PS_H);
  finalize_lrelu<<<1024, 256, 0, stream>>>(partial, mb1, gb1, hm1, hg1);
  conv_path_tap<<<768, 128, 0, stream>>>(hm1, hg1, mP + 2949120, gP + 2949120, partial, 512, 512, PS_H);
  finalize_lrelu<<<1024, 256, 0, stream>>>(partial, mb2, gb2, hm0, hg0);
  conv_path_tap<<<768, 128, 0, stream>>>(hm0, hg0, mP + 5308416, gP + 5308416, partial, 512, 512, PS_H);
  finalize_lrelu<<<1024, 256, 0, stream>>>(partial, mb3, gb3, hm1, hg1);
  conv_path_tap<<<192, 128, 0, stream>>>(hm1, hg1, mP + 7667712, gP + 7667712, partial, 512, 128, PS_H);
  finalize_l5<<<256, 256, 0, stream>>>(partial, fb, lb, fsm, lsm);

  // ---- noise path ----
  fold_all<<<3392, 256, 0, stream>>>(nw0, nw1, nw2, nw3, nlw, E1, E2, E3, E4, Pnl);
  conv_noise<1, 64, 128><<<256, 256, 0, stream>>>(xm3, E1, nb0, l1out, 64, PS_X, 1048576);
  conv_noise<2, 64, 512><<<256, 256, 0, stream>>>(l1out, E2, nb1, l2out, 128, 1048576, 2097152);
  conv_noise<2, 128, 512><<<256, 256, 0, stream>>>(l2out, E3, nb2, l3out, 256, 2097152, 4194304);
  conv_noise<2, 128, 512><<<512, 256, 0, stream>>>(l3out, E4, nb3, l4act, 512, 4194304, 8388608);

  conv_nl_mfma<<<256, 128, 0, stream>>>(l4act, Pnl, nlb, nl);

  // ---- filtered noise frames ----
  noise_filter<<<256, 64, 0, stream>>>(noise, nl, filt);

  // ---- oscillator bank + final sum ----
  osc_phase<<<dim3(128, 16), 256, 0, stream>>>(fsm, phaseBase);
  osc_sum<<<dim3(256, 16), 128, 0, stream>>>(fsm, lsm, phaseBase, filt, out);
}

// Round 10
// 535.730 us; speedup vs baseline: 1.0355x; 1.0355x over previous
//
#include <hip/hip_runtime.h>
#include <math.h>

#define ACT_LRELU  0
#define ACT_SIGMAP 1
#define ACT_SQUARE 2

typedef __attribute__((ext_vector_type(8))) short v8s;
typedef __attribute__((ext_vector_type(4))) short v4s;
typedef __attribute__((ext_vector_type(16))) float f32x16;

static __device__ __forceinline__ float lrelu(float x) { return x >= 0.f ? x : 0.2f * x; }

static __device__ __forceinline__ short bf16rne(float x) {
  unsigned u = __float_as_uint(x);
  unsigned r = (u + 0x7FFFu + ((u >> 16) & 1u)) >> 16;
  return (short)r;
}
static __device__ __forceinline__ float bf16tof(short h) {
  return __uint_as_float(((unsigned)(unsigned short)h) << 16);
}
static __device__ __forceinline__ void split3(float v, short& h, short& l, short& q) {
  h = bf16rne(v); float r1 = v - bf16tof(h);
  l = bf16rne(r1); float r2 = r1 - bf16tof(l);
  q = bf16rne(r2);
}

// -------------------------------------------------------------------------
// prep_acts: x[b][128][64] -> xm3[pl][b][t][ci], 3 bf16 planes (~exact fp32)
// -------------------------------------------------------------------------
__global__ void __launch_bounds__(256) prep_acts(
    const float* __restrict__ x, short* __restrict__ xm3)
{
  int e = blockIdx.x * 256 + threadIdx.x;
  if (e >= 131072) return;
  int b = e >> 13, rem = e & 8191, t = rem >> 7, ci = rem & 127;
  float v = x[((size_t)(b * 128) + ci) * 64 + t];
  short h, l, q; split3(v, h, l, q);
  size_t o = ((size_t)(b * 64) + t) * 128 + ci;
  xm3[0 * 131072 + o] = h;
  xm3[1 * 131072 + o] = l;
  xm3[2 * 131072 + o] = q;
}

// -------------------------------------------------------------------------
// prep_panels (VECTORIZED): each thread handles 8 consecutive ci of one
// (path, layer, co): reads 24 contiguous floats, writes 9 x 16B v8s stores.
// P[pl][co][tap*Cin+ci], 3 bf16 planes, tap-major K.
// -------------------------------------------------------------------------
__global__ void __launch_bounds__(256) prep_panels(
    const float* mw0, const float* mw1, const float* mw2, const float* mw3, const float* fw,
    const float* gw0, const float* gw1, const float* gw2, const float* gw3, const float* lw,
    short* __restrict__ mP, short* __restrict__ gP)
{
  int i = blockIdx.x * 256 + threadIdx.x;
  const int PER = 114688;                  // 917504 / 8
  if (i >= 2 * PER) return;
  int path = i >= PER ? 1 : 0;
  int r = i - path * PER;
  int layer, Cin, Cout; size_t poff;
  if (r < 8192)        { layer = 0;              Cin = 128; Cout = 512; poff = 0; }
  else if (r < 40960)  { layer = 1; r -= 8192;   Cin = 512; Cout = 512; poff = 589824; }
  else if (r < 73728)  { layer = 2; r -= 40960;  Cin = 512; Cout = 512; poff = 2949120; }
  else if (r < 106496) { layer = 3; r -= 73728;  Cin = 512; Cout = 512; poff = 5308416; }
  else                 { layer = 4; r -= 106496; Cin = 512; Cout = 128; poff = 7667712; }
  const float* Wm[5] = {mw0, mw1, mw2, mw3, fw};
  const float* Wg[5] = {gw0, gw1, gw2, gw3, lw};
  const float* W = path ? Wg[layer] : Wm[layer];
  short* P = (path ? gP : mP) + poff;
  const int nci8 = Cin >> 3;
  int co = r / nci8, ci = (r - co * nci8) * 8;
  const int K3 = 3 * Cin;
  const float* wp = W + (size_t)(co * Cin + ci) * 3;   // 24 contiguous floats
  v8s hv[3], lv[3], qv[3];
#pragma unroll
  for (int j = 0; j < 8; ++j)
#pragma unroll
    for (int tap = 0; tap < 3; ++tap) {
      short h, l, q; split3(wp[j * 3 + tap], h, l, q);
      hv[tap][j] = h; lv[tap][j] = l; qv[tap][j] = q;
    }
#pragma unroll
  for (int tap = 0; tap < 3; ++tap) {
    size_t base = (size_t)co * K3 + tap * Cin + ci;
    *(v8s*)&P[(size_t)0 * Cout * K3 + base] = hv[tap];
    *(v8s*)&P[(size_t)1 * Cout * K3 + base] = lv[tap];
    *(v8s*)&P[(size_t)2 * Cout * K3 + base] = qv[tap];
  }
}

// -------------------------------------------------------------------------
// m/g path conv, tap-split: each block computes ONE tap's partial GEMM
// (f32) for a 64x64 tile. 2 waves (wave tile 32x64), BK=32, T14 staging.
// m path: 6 products; g path: 3. partial[(tap*2+path)*1024 + gn][co].
// -------------------------------------------------------------------------
__global__ void __launch_bounds__(128, 2) conv_path_tap(
    const short* __restrict__ actM, const short* __restrict__ actG,
    const short* __restrict__ Pm, const short* __restrict__ Pg,
    float* __restrict__ partial, int Cin, int Cout, int psIn)
{
  const int mtiles = Cout >> 6;
  const int nblk = 2 * mtiles * 16 * 3;
  const int Q = nblk >> 3;
  int d = blockIdx.x;
  int idx = (d & 7) * Q + (d >> 3);
  int mt = idx % mtiles; int r = idx / mtiles;
  int nt = r & 15; r >>= 4;
  int tap = r % 3; int path = r / 3;

  const short* act = path ? actG : actM;
  const short* P   = path ? Pg : Pm;
  const int K3 = 3 * Cin;
  const int co0 = mt * 64;
  const int NT  = Cin >> 5;
  const int npl = path ? 2 : 3;

  const int tid = threadIdx.x;
  const int w = tid >> 6;
  const int l = tid & 63;

  __shared__ __align__(16) short Al[3][64 * 40];
  __shared__ __align__(16) short Bl[3][64 * 40];

  f32x16 acc[2] = {};
  v8s rA[3][2], rB[3][2];

  auto LOADA = [&](int t) {
    int ci0 = t << 5;
#pragma unroll
    for (int pl = 0; pl < 3; ++pl) {
      if (pl >= npl) break;
#pragma unroll
      for (int it = 0; it < 2; ++it) {
        int e = it * 128 + tid;
        int row = e >> 2, c8 = e & 3;
        rA[pl][it] = *(const v8s*)&P[(size_t)pl * Cout * K3 + (size_t)(co0 + row) * K3
                                     + tap * Cin + ci0 + c8 * 8];
      }
    }
  };
  auto LOADB = [&](int t) {
    int ci0 = t << 5;
#pragma unroll
    for (int pl = 0; pl < 3; ++pl) {
      if (pl >= npl) break;
#pragma unroll
      for (int it = 0; it < 2; ++it) {
        int e = it * 128 + tid;
        int n = e >> 2, c8 = e & 3;
        int trow = n + tap - 1;
        v8s vv = {};
        if (trow >= 0 && trow < 64)
          vv = *(const v8s*)&act[(size_t)pl * psIn + ((size_t)(nt * 64 + trow)) * Cin
                                 + ci0 + c8 * 8];
        rB[pl][it] = vv;
      }
    }
  };
  auto WRITE = [&]() {
#pragma unroll
    for (int pl = 0; pl < 3; ++pl) {
      if (pl >= npl) break;
#pragma unroll
      for (int it = 0; it < 2; ++it) {
        int e = it * 128 + tid;
        *(v8s*)&Al[pl][(e >> 2) * 40 + (e & 3) * 8] = rA[pl][it];
        *(v8s*)&Bl[pl][(e >> 2) * 40 + (e & 3) * 8] = rB[pl][it];
      }
    }
  };

  LOADA(0); LOADB(0);
  WRITE();
  __syncthreads();

  for (int t = 0; t < NT; ++t) {
    if (t + 1 < NT) { LOADA(t + 1); LOADB(t + 1); }
    const int lr = l & 31, lh = (l >> 5) * 8;
#pragma unroll
    for (int kk = 0; kk < 2; ++kk) {
      const int ao = (w * 32 + lr) * 40 + kk * 16 + lh;
      v8s a0 = *(const v8s*)&Al[0][ao];
      v8s a1 = *(const v8s*)&Al[1][ao];
#pragma unroll
      for (int fn = 0; fn < 2; ++fn) {
        const int bo = (fn * 32 + lr) * 40 + kk * 16 + lh;
        v8s b0 = *(const v8s*)&Bl[0][bo];
        v8s b1 = *(const v8s*)&Bl[1][bo];
        acc[fn] = __builtin_amdgcn_mfma_f32_32x32x16_bf16(a0, b0, acc[fn], 0, 0, 0);
        acc[fn] = __builtin_amdgcn_mfma_f32_32x32x16_bf16(a0, b1, acc[fn], 0, 0, 0);
        acc[fn] = __builtin_amdgcn_mfma_f32_32x32x16_bf16(a1, b0, acc[fn], 0, 0, 0);
        if (path == 0) {
          v8s a2 = *(const v8s*)&Al[2][ao];
          v8s b2 = *(const v8s*)&Bl[2][bo];
          acc[fn] = __builtin_amdgcn_mfma_f32_32x32x16_bf16(a1, b1, acc[fn], 0, 0, 0);
          acc[fn] = __builtin_amdgcn_mfma_f32_32x32x16_bf16(a0, b2, acc[fn], 0, 0, 0);
          acc[fn] = __builtin_amdgcn_mfma_f32_32x32x16_bf16(a2, b0, acc[fn], 0, 0, 0);
        }
      }
    }
    __syncthreads();
    if (t + 1 < NT) { WRITE(); __syncthreads(); }
  }

  const int hi4 = 4 * (l >> 5);
  const size_t pbase = (size_t)(tap * 2 + path) * 1024;
#pragma unroll
  for (int fn = 0; fn < 2; ++fn) {
    int gn = nt * 64 + fn * 32 + (l & 31);
#pragma unroll
    for (int q4 = 0; q4 < 4; ++q4) {
      int co = co0 + w * 32 + q4 * 8 + hi4;
      float4 v = {acc[fn][q4 * 4 + 0], acc[fn][q4 * 4 + 1],
                  acc[fn][q4 * 4 + 2], acc[fn][q4 * 4 + 3]};
      *(float4*)&partial[(pbase + gn) * Cout + co] = v;
    }
  }
}

// -------------------------------------------------------------------------
// finalize (LRELU layers): sum 3 tap partials + bias, lrelu, split3 ->
// 3-plane bf16 activations [pl][b][t][512].
// -------------------------------------------------------------------------
__global__ void __launch_bounds__(256) finalize_lrelu(
    const float* __restrict__ partial,
    const float* __restrict__ BsM, const float* __restrict__ BsG,
    short* __restrict__ soutM, short* __restrict__ soutG)
{
  int e = blockIdx.x * 256 + threadIdx.x;   // < 262144
  int c4 = e & 127, gn = (e >> 7) & 1023, path = e >> 17;
  const float* Bs = path ? BsG : BsM;
  short* sout = path ? soutG : soutM;
  size_t base = ((size_t)(path) * 1024 + gn) * 512 + c4 * 4;
  const size_t TS = (size_t)2 * 1024 * 512;
  float4 s0 = *(const float4*)&partial[base];
  float4 s1 = *(const float4*)&partial[base + TS];
  float4 s2 = *(const float4*)&partial[base + 2 * TS];
  float4 bi = *(const float4*)&Bs[c4 * 4];
  const float* p0 = &s0.x; const float* p1 = &s1.x;
  const float* p2 = &s2.x; const float* pb = &bi.x;
  v4s h4, l4, q4v;
#pragma unroll
  for (int j = 0; j < 4; ++j) {
    float z = lrelu(p0[j] + p1[j] + p2[j] + pb[j]);
    short h, lo, qq; split3(z, h, lo, qq);
    h4[j] = h; l4[j] = lo; q4v[j] = qq;
  }
  size_t o = (size_t)gn * 512 + c4 * 4;
  *(v4s*)&sout[0 * 524288 + o] = h4;
  *(v4s*)&sout[1 * 524288 + o] = l4;
  *(v4s*)&sout[2 * 524288 + o] = q4v;
}

// -------------------------------------------------------------------------
// finalize (layer 5): m -> SIGMAP band map into fsm[b][co][t];
//                     g -> squared into lsm[b][co][t].  Cout=128.
// -------------------------------------------------------------------------
__global__ void __launch_bounds__(256) finalize_l5(
    const float* __restrict__ partial,
    const float* __restrict__ fb, const float* __restrict__ lb,
    float* __restrict__ fsm, float* __restrict__ lsm)
{
  __shared__ float bandS[2][128];
  int tid = threadIdx.x;
  if (tid < 128) {
    double lg = log(551.25);
    double stop  = 20.0 * exp(lg * (double)tid / 127.0);
    double start = (tid == 0) ? 0.0 : 20.0 * exp(lg * (double)(tid - 1) / 127.0);
    bandS[0][tid] = (float)start;
    bandS[1][tid] = (float)(stop - start);
  }
  __syncthreads();

  int e = blockIdx.x * 256 + tid;   // < 65536
  int c4 = e & 31, gn = (e >> 5) & 1023, path = e >> 15;
  size_t base = ((size_t)(path) * 1024 + gn) * 128 + c4 * 4;
  const size_t TS = (size_t)2 * 1024 * 128;
  float4 s0 = *(const float4*)&partial[base];
  float4 s1 = *(const float4*)&partial[base + TS];
  float4 s2 = *(const float4*)&partial[base + 2 * TS];
  float4 bi = *(const float4*)&((path ? lb : fb)[c4 * 4]);
  const float* p0 = &s0.x; const float* p1 = &s1.x;
  const float* p2 = &s2.x; const float* pb = &bi.x;
  int b = gn >> 6, t = gn & 63;
#pragma unroll
  for (int j = 0; j < 4; ++j) {
    int co = c4 * 4 + j;
    float z = p0[j] + p1[j] + p2[j] + pb[j];
    if (path == 0)
      fsm[((size_t)(b * 128) + co) * 64 + t] = bandS[0][co] + bandS[1][co] / (1.f + expf(-z));
    else
      lsm[((size_t)(b * 128) + co) * 64 + t] = z * z;
  }
}

// -------------------------------------------------------------------------
// fold_all (VECTORIZED): each thread handles 8 consecutive ci. Noise layers:
// reads 56 contiguous floats, writes 16 x 16B v8s; nl panel: 24 floats, 6 v8s.
// -------------------------------------------------------------------------
__global__ void __launch_bounds__(256) fold_all(
    const float* __restrict__ nw0, const float* __restrict__ nw1,
    const float* __restrict__ nw2, const float* __restrict__ nw3,
    const float* __restrict__ nlw,
    short* __restrict__ E1, short* __restrict__ E2,
    short* __restrict__ E3, short* __restrict__ E4,
    short* __restrict__ Pnl)
{
  int i = blockIdx.x * 256 + threadIdx.x;
  if (i >= 106496) {
    if (i >= 108544) return;
    int idx = i - 106496;               // [0, 2048): co = idx>>6, ci8 = idx&63
    int co = idx >> 6, ci = (idx & 63) * 8;
    v8s hv[3], lv[3];
#pragma unroll
    for (int j = 0; j < 8; ++j)
#pragma unroll
      for (int tap = 0; tap < 3; ++tap) {
        float v = (co < 17) ? nlw[((size_t)(co * 512 + ci + j)) * 3 + tap] : 0.f;
        short h = bf16rne(v);
        hv[tap][j] = h;
        lv[tap][j] = bf16rne(v - bf16tof(h));
      }
#pragma unroll
    for (int tap = 0; tap < 3; ++tap) {
      *(v8s*)&Pnl[(size_t)(0 * 32 + co) * 1536 + tap * 512 + ci] = hv[tap];
      *(v8s*)&Pnl[(size_t)(1 * 32 + co) * 1536 + tap * 512 + ci] = lv[tap];
    }
    return;
  }
  const float* W; short* Ag; int Cin; int idx;
  if (i < 8192)        { W = nw0; Ag = E1; Cin = 128; idx = i; }
  else if (i < 40960)  { W = nw1; Ag = E2; Cin = 512; idx = i - 8192; }
  else if (i < 73728)  { W = nw2; Ag = E3; Cin = 512; idx = i - 40960; }
  else                 { W = nw3; Ag = E4; Cin = 512; idx = i - 73728; }
  const int nci8 = Cin >> 3;
  int co = idx / nci8, ci = (idx - co * nci8) * 8;
  const float* wp = W + (size_t)(co * Cin + ci) * 7;   // 56 contiguous floats
  const int K = Cin * 4;
  v8s he[4], le[4], ho[4], lo4[4];
#pragma unroll
  for (int j = 0; j < 8; ++j) {
    const float* w = wp + j * 7;
    float fe[4] = {w[0],        w[1] + w[2], w[3] + w[4], w[5] + w[6]};
    float fo[4] = {w[0] + w[1], w[2] + w[3], w[4] + w[5], w[6]};
#pragma unroll
    for (int q = 0; q < 4; ++q) {
      short h1 = bf16rne(fe[q]);
      he[q][j] = h1; le[q][j] = bf16rne(fe[q] - bf16tof(h1));
      short h2 = bf16rne(fo[q]);
      ho[q][j] = h2; lo4[q][j] = bf16rne(fo[q] - bf16tof(h2));
    }
  }
#pragma unroll
  for (int q = 0; q < 4; ++q) {
    size_t kbase = (size_t)q * Cin + ci;
    *(v8s*)&Ag[((size_t)(0 * 512 + co)) * K + kbase] = he[q];    // par0 hi
    *(v8s*)&Ag[((size_t)(1 * 512 + co)) * K + kbase] = le[q];    // par0 lo
    *(v8s*)&Ag[((size_t)(2 * 512 + co)) * K + kbase] = ho[q];    // par1 hi
    *(v8s*)&Ag[((size_t)(3 * 512 + co)) * K + kbase] = lo4[q];   // par1 lo
  }
}

// -------------------------------------------------------------------------
// Noise conv: 2-plane split-bf16 MFMA GEMM (hh,hl,lh), 32x32x16, T14 async.
// Always writes 2-plane bf16 [pl][b][t][512] for the next consumer.
// -------------------------------------------------------------------------
template<int MF, int BNS, int CIN>
__global__ void __launch_bounds__(256, 2) conv_noise(
    const short* __restrict__ actIn, const short* __restrict__ Ag,
    const float* __restrict__ Bs, short* __restrict__ actOut,
    int Sin, int psIn, int psOut)
{
  constexpr int NF   = BNS / 64;
  constexpr int BM   = MF * 64;
  constexpr int AITS = BM / 32;
  constexpr int BITS = BNS / 32;
  constexpr int K    = CIN * 4;
  constexpr int nci  = CIN / 64;
  constexpr int NT   = 4 * nci;
  const int mtiles = 512 / BM;
  const int stiles = Sin / BNS;
  const int nblk = mtiles * 2 * 16 * stiles;
  const int Q = nblk >> 3;
  int d = blockIdx.x;
  int idx = (d & 7) * Q + (d >> 3);
  int mt = idx % mtiles;
  int t1 = idx / mtiles;
  int par = t1 & 1;
  int rest = t1 >> 1;
  int st = rest % stiles;
  int b = rest / stiles;

  const int co0 = mt * BM;
  const int s0 = st * BNS;
  const int soff = par ? -1 : -2;

  const int tid = threadIdx.x;
  const int w = tid >> 6, wm = w & 1, wn = w >> 1;
  const int l = tid & 63;

  __shared__ __align__(16) short Al[2][BM * 72];
  __shared__ __align__(16) short Bl[2][BNS * 72];

  f32x16 acc[MF][NF] = {};
  v8s rA[2][AITS], rB[2][BITS];

  auto LOADA = [&](int t) {
    int q = t / nci, ci0 = (t % nci) << 6;
#pragma unroll
    for (int pl = 0; pl < 2; ++pl)
#pragma unroll
      for (int it = 0; it < AITS; ++it) {
        int e = it * 256 + tid;
        int row = e >> 3, c8 = e & 7;
        rA[pl][it] = *(const v8s*)&Ag[((size_t)((par * 2 + pl) * 512 + co0 + row)) * K
                                      + q * CIN + ci0 + c8 * 8];
      }
  };
  auto LOADB = [&](int t) {
    int q = t / nci, ci0 = (t % nci) << 6;
#pragma unroll
    for (int pl = 0; pl < 2; ++pl)
#pragma unroll
      for (int it = 0; it < BITS; ++it) {
        int e = it * 256 + tid;
        int n = e >> 3, c8 = e & 7;
        int srow = s0 + n + q + soff;
        v8s vv = {};
        if (srow >= 0 && srow < Sin)
          vv = *(const v8s*)&actIn[(size_t)pl * psIn + ((size_t)(b * Sin + srow)) * CIN
                                   + ci0 + c8 * 8];
        rB[pl][it] = vv;
      }
  };
  auto WRITE = [&]() {
#pragma unroll
    for (int pl = 0; pl < 2; ++pl) {
#pragma unroll
      for (int it = 0; it < AITS; ++it) {
        int e = it * 256 + tid;
        *(v8s*)&Al[pl][(e >> 3) * 72 + (e & 7) * 8] = rA[pl][it];
      }
#pragma unroll
      for (int it = 0; it < BITS; ++it) {
        int e = it * 256 + tid;
        *(v8s*)&Bl[pl][(e >> 3) * 72 + (e & 7) * 8] = rB[pl][it];
      }
    }
  };

  LOADA(0); LOADB(0);
  WRITE();
  __syncthreads();

  for (int t = 0; t < NT; ++t) {
    if (t + 1 < NT) { LOADA(t + 1); LOADB(t + 1); }
    const int lr = l & 31, lh = (l >> 5) * 8;
#pragma unroll
    for (int kk = 0; kk < 4; ++kk) {
      v8s ah[MF], al[MF], bh[NF], bl[NF];
#pragma unroll
      for (int fm = 0; fm < MF; ++fm) {
        int ab = (wm * (MF * 32) + fm * 32 + lr) * 72 + kk * 16 + lh;
        ah[fm] = *(const v8s*)&Al[0][ab];
        al[fm] = *(const v8s*)&Al[1][ab];
      }
#pragma unroll
      for (int fn = 0; fn < NF; ++fn) {
        int bb = (wn * (BNS / 2) + fn * 32 + lr) * 72 + kk * 16 + lh;
        bh[fn] = *(const v8s*)&Bl[0][bb];
        bl[fn] = *(const v8s*)&Bl[1][bb];
      }
#pragma unroll
      for (int fm = 0; fm < MF; ++fm)
#pragma unroll
        for (int fn = 0; fn < NF; ++fn) {
          acc[fm][fn] = __builtin_amdgcn_mfma_f32_32x32x16_bf16(ah[fm], bh[fn], acc[fm][fn], 0, 0, 0);
          acc[fm][fn] = __builtin_amdgcn_mfma_f32_32x32x16_bf16(ah[fm], bl[fn], acc[fm][fn], 0, 0, 0);
          acc[fm][fn] = __builtin_amdgcn_mfma_f32_32x32x16_bf16(al[fm], bh[fn], acc[fm][fn], 0, 0, 0);
        }
    }
    __syncthreads();
    if (t + 1 < NT) { WRITE(); __syncthreads(); }
  }

  // epilogue: always 2-plane bf16 [pl][b][t=2s+par][512]
  const int hi4 = 4 * (l >> 5);
  const int T2 = 2 * Sin;
#pragma unroll
  for (int fm = 0; fm < MF; ++fm)
#pragma unroll
    for (int q4 = 0; q4 < 4; ++q4) {
      int co = co0 + wm * (MF * 32) + fm * 32 + q4 * 8 + hi4;
      float4 bia = *(const float4*)&Bs[co];
      const float* bp = &bia.x;
#pragma unroll
      for (int fn = 0; fn < NF; ++fn) {
        int s_l = wn * (BNS / 2) + fn * 32 + (l & 31);
        int t = 2 * (s0 + s_l) + par;
        v4s h4, l4;
#pragma unroll
        for (int j = 0; j < 4; ++j) {
          float z = lrelu(acc[fm][fn][q4 * 4 + j] + bp[j]);
          short h = bf16rne(z);
          h4[j] = h;
          l4[j] = bf16rne(z - bf16tof(h));
        }
        size_t o = ((size_t)(b * T2) + t) * 512 + co;
        *(v4s*)&actOut[0 * (size_t)psOut + o] = h4;
        *(v4s*)&actOut[1 * (size_t)psOut + o] = l4;
      }
    }
}

// -------------------------------------------------------------------------
// conv_nl as split-bf16 MFMA GEMM: M=32 (17 padded), K=3*512 via shifted-row
// LDS taps, N=16x1024. BN=64, 2 waves, grid 256. Output squared.
// -------------------------------------------------------------------------
#define NL_PS4 8388608   // l4act plane stride (shorts)

__global__ void __launch_bounds__(128) conv_nl_mfma(
    const short* __restrict__ act, const short* __restrict__ Pnl,
    const float* __restrict__ Bs, float* __restrict__ outNl)
{
  const int bid = blockIdx.x;
  const int b = bid >> 4, t0 = (bid & 15) << 6;
  const int tid = threadIdx.x;
  const int w = tid >> 6;
  const int l = tid & 63;

  __shared__ __align__(16) short Al[2 * 3 * 32 * 72];
  __shared__ __align__(16) short Bl[2 * 66 * 72];

  f32x16 acc = {};

  for (int ci0 = 0; ci0 < 512; ci0 += 64) {
    for (int e = tid; e < 1536; e += 128) {
      int c8 = e & 7, row = e >> 3;
      int pl = row >= 96;
      int r2 = row - pl * 96;
      int tap = r2 >> 5, co = r2 & 31;
      v8s vv = *(const v8s*)&Pnl[(size_t)(pl * 32 + co) * 1536 + tap * 512 + ci0 + c8 * 8];
      *(v8s*)&Al[row * 72 + c8 * 8] = vv;
    }
    for (int e = tid; e < 1056; e += 128) {
      int c8 = e & 7, r = (e >> 3) % 66, pl = (e >> 3) / 66;
      int t = t0 + r - 1;
      v8s vv = {};
      if (t >= 0 && t < 1024)
        vv = *(const v8s*)&act[(size_t)pl * NL_PS4 + ((size_t)(b << 10) + t) * 512 + ci0 + c8 * 8];
      *(v8s*)&Bl[(pl * 66 + r) * 72 + c8 * 8] = vv;
    }
    __syncthreads();
    const int lr = l & 31, lh = (l >> 5) * 8;
#pragma unroll
    for (int kk = 0; kk < 4; ++kk)
#pragma unroll
      for (int tap = 0; tap < 3; ++tap) {
        v8s a_h = *(const v8s*)&Al[((0 * 3 + tap) * 32 + lr) * 72 + kk * 16 + lh];
        v8s a_l = *(const v8s*)&Al[((1 * 3 + tap) * 32 + lr) * 72 + kk * 16 + lh];
        int brow = w * 32 + lr + tap;
        v8s b_h = *(const v8s*)&Bl[(0 * 66 + brow) * 72 + kk * 16 + lh];
        v8s b_l = *(const v8s*)&Bl[(1 * 66 + brow) * 72 + kk * 16 + lh];
        acc = __builtin_amdgcn_mfma_f32_32x32x16_bf16(a_h, b_h, acc, 0, 0, 0);
        acc = __builtin_amdgcn_mfma_f32_32x32x16_bf16(a_h, b_l, acc, 0, 0, 0);
        acc = __builtin_amdgcn_mfma_f32_32x32x16_bf16(a_l, b_h, acc, 0, 0, 0);
      }
    __syncthreads();
  }

  const int t = t0 + w * 32 + (l & 31);
  const int hi4 = 4 * (l >> 5);
#pragma unroll
  for (int q4 = 0; q4 < 4; ++q4) {
#pragma unroll
    for (int j = 0; j < 4; ++j) {
      int co = q4 * 8 + hi4 + j;
      if (co < 17) {
        float z = acc[q4 * 4 + j] + Bs[co];
        outNl[((size_t)(b * 17) + co) * 1024 + t] = z * z;
      }
    }
  }
}

// -------------------------------------------------------------------------
// Noise bank: per 32-sample frame, 17-bin real DFT * mags, inverse, store.
// -------------------------------------------------------------------------
__global__ void __launch_bounds__(64) noise_filter(
    const float* __restrict__ noise, const float* __restrict__ mags,
    float* __restrict__ filt)
{
  __shared__ float ct[32], st[32];
  int tid = threadIdx.x;
  if (tid < 32) {
    double a = (double)tid * (3.14159265358979323846 / 16.0);
    ct[tid] = (float)cos(a);
    st[tid] = (float)sin(a);
  }
  __syncthreads();

  int fidx = blockIdx.x * 64 + tid;
  int b = fidx >> 10, i = fidx & 1023;

  float xv[32];
#pragma unroll
  for (int n = 0; n < 32; ++n) {
    int idx = i * 16 + n;
    xv[n] = (idx < 16384) ? noise[(size_t)b * 16384 + idx] : 0.f;
  }

  float Yr[17], Yi[17];
#pragma unroll
  for (int k = 0; k <= 16; ++k) {
    float xr = 0.f, xi = 0.f;
    int kk = 0;
#pragma unroll
    for (int n = 0; n < 32; ++n) {
      xr += xv[n] * ct[kk];
      xi -= xv[n] * st[kk];
      kk = (kk + k) & 31;
    }
    float m = mags[((size_t)b * 17 + k) * 1024 + i];
    Yr[k] = xr * m;
    Yi[k] = xi * m;
  }

  float* fo = filt + ((size_t)b * 1024 + i) * 32;
#pragma unroll
  for (int n = 0; n < 32; ++n) {
    float v = Yr[0] + ((n & 1) ? -Yr[16] : Yr[16]);
    int kk = n;
#pragma unroll
    for (int k = 1; k <= 15; ++k) {
      v += 2.f * (Yr[k] * ct[kk] - Yi[k] * st[kk]);
      kk = (kk + n) & 31;
    }
    fo[n] = v * (1.f / 32.f);
  }
}

// -------------------------------------------------------------------------
// Oscillator bank (3-point lerp endpoints + f64 chunk base + f32 Kahan).
// -------------------------------------------------------------------------
static __device__ __forceinline__ int clamp64(int i) { return i < 0 ? 0 : (i > 63 ? 63 : i); }

__global__ void __launch_bounds__(256) osc_phase(
    const float* __restrict__ fsm, double* __restrict__ phaseBase)
{
  const int o = blockIdx.x, b = blockIdx.y;
  const float* frow = fsm + (size_t)(b * 128 + o) * 64;
  const int c = threadIdx.x;

  const float ic0 = ((float)(c * 64) - 127.5f) * (1.0f / 256.0f);
  const int ilo = (int)floorf(ic0);
  float f0 = frow[clamp64(ilo)], f1 = frow[clamp64(ilo + 1)], f2 = frow[clamp64(ilo + 2)];

  double local = 0.0;
#pragma unroll 8
  for (int j = 0; j < 64; ++j) {
    float ic = ic0 + (float)j * (1.0f / 256.0f);
    float fl = floorf(ic);
    float w  = ic - fl;
    bool hi = ((int)fl) > ilo;
    float fa = hi ? f1 : f0;
    float fb = hi ? f2 : f1;
    float f = fa * (1.f - w) + fb * w;
    f = fminf(fmaxf(f, 20.f), 11025.f);
    local += (double)f;
  }
  local *= (1.0 / 22050.0);

  __shared__ double ps[256];
  ps[c] = local;
  __syncthreads();
  for (int off = 1; off < 256; off <<= 1) {
    double v = (c >= off) ? ps[c - off] : 0.0;
    __syncthreads();
    ps[c] += v;
    __syncthreads();
  }
  phaseBase[(size_t)(b * 128 + o) * 256 + c] = ps[c] - local;
}

__global__ void __launch_bounds__(128) osc_sum(
    const float* __restrict__ fsm, const float* __restrict__ lsm,
    const double* __restrict__ phaseBase, const float* __restrict__ filt,
    float* __restrict__ out)
{
  const int c = blockIdx.x, b = blockIdx.y;
  const int tid = threadIdx.x;
  __shared__ float contrib[128][65];
  __shared__ float part[2][64];
  const int o = tid;
  const float* frow = fsm + (size_t)(b * 128 + o) * 64;
  const float* arow = lsm + (size_t)(b * 128 + o) * 64;

  double pb = phaseBase[(size_t)(b * 128 + o) * 256 + c];
  float fb0 = (float)(pb - floor(pb));

  const float ic0 = ((float)(c * 64) - 127.5f) * (1.0f / 256.0f);
  const int ilo = (int)floorf(ic0);
  float f0 = frow[clamp64(ilo)], f1 = frow[clamp64(ilo + 1)], f2 = frow[clamp64(ilo + 2)];
  float a0 = arow[clamp64(ilo)], a1 = arow[clamp64(ilo + 1)], a2 = arow[clamp64(ilo + 2)];

  float rel = 0.f, comp = 0.f;
#pragma unroll 8
  for (int j = 0; j < 64; ++j) {
    float ic = ic0 + (float)j * (1.0f / 256.0f);
    float fl = floorf(ic);
    float w  = ic - fl;
    bool hi = ((int)fl) > ilo;
    float fa = hi ? f1 : f0;
    float fb = hi ? f2 : f1;
    float f = fa * (1.f - w) + fb * w;
    f = fminf(fmaxf(f, 20.f), 11025.f);
    float y = f * (1.0f / 22050.0f) - comp;
    float t = rel + y;
    comp = (t - rel) - y;
    rel = t;
    float tot = fb0 + rel;
    float frac = tot - floorf(tot);
    float s = sinpif(2.f * frac);
    float aa = hi ? a1 : a0;
    float ab = hi ? a2 : a1;
    float am = aa * (1.f - w) + ab * w;
    contrib[o][j] = s * am;
  }
  __syncthreads();
  int half = tid >> 6, tl = tid & 63;
  float sum = 0.f;
  for (int oo = 0; oo < 64; ++oo) sum += contrib[half * 64 + oo][tl];
  part[half][tl] = sum;
  __syncthreads();
  if (tid < 64) {
    int t = c * 64 + tid;
    float v = part[0][tid] + part[1][tid];
    int i0 = t >> 4, r = t & 15;
    v += filt[((size_t)(b << 10) + i0) * 32 + r];
    if (i0 > 0) v += filt[((size_t)(b << 10) + i0 - 1) * 32 + 16 + r];
    out[(size_t)b * 16384 + t] = v;
  }
}

// -------------------------------------------------------------------------
extern "C" void kernel_launch(void* const* d_in, const int* in_sizes, int n_in,
                              void* d_out, int out_size, void* d_ws, size_t ws_size,
                              hipStream_t stream)
{
  (void)in_sizes; (void)n_in; (void)out_size; (void)ws_size;

  const float* x     = (const float*)d_in[0];
  const float* noise = (const float*)d_in[1];
  const float* mw0 = (const float*)d_in[2];  const float* mb0 = (const float*)d_in[3];
  const float* mw1 = (const float*)d_in[4];  const float* mb1 = (const float*)d_in[5];
  const float* mw2 = (const float*)d_in[6];  const float* mb2 = (const float*)d_in[7];
  const float* mw3 = (const float*)d_in[8];  const float* mb3 = (const float*)d_in[9];
  const float* fw  = (const float*)d_in[10]; const float* fb  = (const float*)d_in[11];
  const float* gw0 = (const float*)d_in[12]; const float* gb0 = (const float*)d_in[13];
  const float* gw1 = (const float*)d_in[14]; const float* gb1 = (const float*)d_in[15];
  const float* gw2 = (const float*)d_in[16]; const float* gb2 = (const float*)d_in[17];
  const float* gw3 = (const float*)d_in[18]; const float* gb3 = (const float*)d_in[19];
  const float* lw  = (const float*)d_in[20]; const float* lb  = (const float*)d_in[21];
  const float* nw0 = (const float*)d_in[22]; const float* nb0 = (const float*)d_in[23];
  const float* nw1 = (const float*)d_in[24]; const float* nb1 = (const float*)d_in[25];
  const float* nw2 = (const float*)d_in[26]; const float* nb2 = (const float*)d_in[27];
  const float* nw3 = (const float*)d_in[28]; const float* nb3 = (const float*)d_in[29];
  const float* nlw = (const float*)d_in[30]; const float* nlb = (const float*)d_in[31];

  // ---- workspace (BYTE offsets; high-water 60,751,872 B < 63 MB cap) ----
  char* W8 = (char*)d_ws;
  short* mP  = (short*)(W8 + 0);
  short* gP  = (short*)(W8 + 16515072);
  short* hm0 = (short*)(W8 + 33030144);
  short* hm1 = (short*)(W8 + 36175872);
  short* hg0 = (short*)(W8 + 39321600);
  short* hg1 = (short*)(W8 + 42467328);
  float* partial = (float*)(W8 + 45613056);  // 12,582,912 B
  short* xm3 = (short*)(W8 + 58720256);
  float* fsm = (float*)(W8 + 59506688);
  float* lsm = (float*)(W8 + 60030976);
  short* Pnl = (short*)(W8 + 60555264);    // 196,608 B

  short* E4  = (short*)(W8 + 0);           // 8,388,608 B
  short* E3  = (short*)(W8 + 33554432);    // 8,388,608 B
  short* E2  = (short*)(W8 + 41943040);    // 8,388,608 B
  short* E1  = (short*)(W8 + 50331648);    // 2,097,152 B
  short* l1out = (short*)(W8 + 52428800);  // 4,194,304 B
  short* l2out = (short*)(W8 + 25165824);  // 8,388,608 B
  short* l3out = (short*)(W8 + 8388608);   // 16,777,216 B
  short* l4act = (short*)(W8 + 25165824);  // 33,554,432 B

  float* nl   = (float*)(W8 + 0);          // 1,114,112 B
  float* filt = (float*)(W8 + 1114112);    // 2,097,152 B
  double* phaseBase = (double*)(W8 + 4194304);  // 4,194,304 B

  float* out = (float*)d_out;

  const int PS_X = 131072;   // xm3 plane stride (shorts)
  const int PS_H = 524288;   // m/g act plane stride (shorts)

  // ---- prep (vectorized 16B stores) ----
  prep_acts<<<512, 256, 0, stream>>>(x, xm3);
  prep_panels<<<896, 256, 0, stream>>>(mw0, mw1, mw2, mw3, fw,
                                       gw0, gw1, gw2, gw3, lw, mP, gP);

  // ---- m/g paths: tap-split MFMA + finalize ----
  conv_path_tap<<<768, 128, 0, stream>>>(xm3, xm3, mP + 0, gP + 0, partial, 128, 512, PS_X);
  finalize_lrelu<<<1024, 256, 0, stream>>>(partial, mb0, gb0, hm0, hg0);
  conv_path_tap<<<768, 128, 0, stream>>>(hm0, hg0, mP + 589824, gP + 589824, partial, 512, 512, PS_H);
  finalize_lrelu<<<1024, 256, 0, stream>>>(partial, mb1, gb1, hm1, hg1);
  conv_path_tap<<<768, 128, 0, stream>>>(hm1, hg1, mP + 2949120, gP + 2949120, partial, 512, 512, PS_H);
  finalize_lrelu<<<1024, 256, 0, stream>>>(partial, mb2, gb2, hm0, hg0);
  conv_path_tap<<<768, 128, 0, stream>>>(hm0, hg0, mP + 5308416, gP + 5308416, partial, 512, 512, PS_H);
  finalize_lrelu<<<1024, 256, 0, stream>>>(partial, mb3, gb3, hm1, hg1);
  conv_path_tap<<<192, 128, 0, stream>>>(hm1, hg1, mP + 7667712, gP + 7667712, partial, 512, 128, PS_H);
  finalize_l5<<<256, 256, 0, stream>>>(partial, fb, lb, fsm, lsm);

  // ---- noise path ----
  fold_all<<<424, 256, 0, stream>>>(nw0, nw1, nw2, nw3, nlw, E1, E2, E3, E4, Pnl);
  conv_noise<1, 64, 128><<<256, 256, 0, stream>>>(xm3, E1, nb0, l1out, 64, PS_X, 1048576);
  conv_noise<2, 64, 512><<<256, 256, 0, stream>>>(l1out, E2, nb1, l2out, 128, 1048576, 2097152);
  conv_noise<2, 128, 512><<<256, 256, 0, stream>>>(l2out, E3, nb2, l3out, 256, 2097152, 4194304);
  conv_noise<2, 128, 512><<<512, 256, 0, stream>>>(l3out, E4, nb3, l4act, 512, 4194304, 8388608);

  conv_nl_mfma<<<256, 128, 0, stream>>>(l4act, Pnl, nlb, nl);

  // ---- filtered noise frames ----
  noise_filter<<<256, 64, 0, stream>>>(noise, nl, filt);

  // ---- oscillator bank + final sum ----
  osc_phase<<<dim3(128, 16), 256, 0, stream>>>(fsm, phaseBase);
  osc_sum<<<dim3(256, 16), 128, 0, stream>>>(fsm, lsm, phaseBase, filt, out);
}

// Round 11
// 514.923 us; speedup vs baseline: 1.0773x; 1.0404x over previous
//
#include <hip/hip_runtime.h>
#include <math.h>

#define ACT_LRELU  0
#define ACT_SIGMAP 1
#define ACT_SQUARE 2

typedef __attribute__((ext_vector_type(8))) short v8s;
typedef __attribute__((ext_vector_type(4))) short v4s;
typedef __attribute__((ext_vector_type(16))) float f32x16;

static __device__ __forceinline__ float lrelu(float x) { return x >= 0.f ? x : 0.2f * x; }

static __device__ __forceinline__ short bf16rne(float x) {
  unsigned u = __float_as_uint(x);
  unsigned r = (u + 0x7FFFu + ((u >> 16) & 1u)) >> 16;
  return (short)r;
}
static __device__ __forceinline__ float bf16tof(short h) {
  return __uint_as_float(((unsigned)(unsigned short)h) << 16);
}
static __device__ __forceinline__ void split3(float v, short& h, short& l, short& q) {
  h = bf16rne(v); float r1 = v - bf16tof(h);
  l = bf16rne(r1); float r2 = r1 - bf16tof(l);
  q = bf16rne(r2);
}

// -------------------------------------------------------------------------
// prep_acts: x[b][128][64] -> xm3[pl][b][t][ci], 3 bf16 planes (~exact fp32)
// -------------------------------------------------------------------------
__global__ void __launch_bounds__(256) prep_acts(
    const float* __restrict__ x, short* __restrict__ xm3)
{
  int e = blockIdx.x * 256 + threadIdx.x;
  if (e >= 131072) return;
  int b = e >> 13, rem = e & 8191, t = rem >> 7, ci = rem & 127;
  float v = x[((size_t)(b * 128) + ci) * 64 + t];
  short h, l, q; split3(v, h, l, q);
  size_t o = ((size_t)(b * 64) + t) * 128 + ci;
  xm3[0 * 131072 + o] = h;
  xm3[1 * 131072 + o] = l;
  xm3[2 * 131072 + o] = q;
}

// -------------------------------------------------------------------------
// prep_panels (vectorized): thread = 8 consecutive ci of one (path,layer,co).
// -------------------------------------------------------------------------
__global__ void __launch_bounds__(256) prep_panels(
    const float* mw0, const float* mw1, const float* mw2, const float* mw3, const float* fw,
    const float* gw0, const float* gw1, const float* gw2, const float* gw3, const float* lw,
    short* __restrict__ mP, short* __restrict__ gP)
{
  int i = blockIdx.x * 256 + threadIdx.x;
  const int PER = 114688;
  if (i >= 2 * PER) return;
  int path = i >= PER ? 1 : 0;
  int r = i - path * PER;
  int layer, Cin, Cout; size_t poff;
  if (r < 8192)        { layer = 0;              Cin = 128; Cout = 512; poff = 0; }
  else if (r < 40960)  { layer = 1; r -= 8192;   Cin = 512; Cout = 512; poff = 589824; }
  else if (r < 73728)  { layer = 2; r -= 40960;  Cin = 512; Cout = 512; poff = 2949120; }
  else if (r < 106496) { layer = 3; r -= 73728;  Cin = 512; Cout = 512; poff = 5308416; }
  else                 { layer = 4; r -= 106496; Cin = 512; Cout = 128; poff = 7667712; }
  const float* Wm[5] = {mw0, mw1, mw2, mw3, fw};
  const float* Wg[5] = {gw0, gw1, gw2, gw3, lw};
  const float* W = path ? Wg[layer] : Wm[layer];
  short* P = (path ? gP : mP) + poff;
  const int nci8 = Cin >> 3;
  int co = r / nci8, ci = (r - co * nci8) * 8;
  const int K3 = 3 * Cin;
  const float* wp = W + (size_t)(co * Cin + ci) * 3;
  v8s hv[3], lv[3], qv[3];
#pragma unroll
  for (int j = 0; j < 8; ++j)
#pragma unroll
    for (int tap = 0; tap < 3; ++tap) {
      short h, l, q; split3(wp[j * 3 + tap], h, l, q);
      hv[tap][j] = h; lv[tap][j] = l; qv[tap][j] = q;
    }
#pragma unroll
  for (int tap = 0; tap < 3; ++tap) {
    size_t base = (size_t)co * K3 + tap * Cin + ci;
    *(v8s*)&P[(size_t)0 * Cout * K3 + base] = hv[tap];
    *(v8s*)&P[(size_t)1 * Cout * K3 + base] = lv[tap];
    *(v8s*)&P[(size_t)2 * Cout * K3 + base] = qv[tap];
  }
}

// -------------------------------------------------------------------------
// m/g path conv, tap-split (unchanged structure; plane loops guard, no break)
// -------------------------------------------------------------------------
__global__ void __launch_bounds__(128, 2) conv_path_tap(
    const short* __restrict__ actM, const short* __restrict__ actG,
    const short* __restrict__ Pm, const short* __restrict__ Pg,
    float* __restrict__ partial, int Cin, int Cout, int psIn)
{
  const int mtiles = Cout >> 6;
  const int nblk = 2 * mtiles * 16 * 3;
  const int Q = nblk >> 3;
  int d = blockIdx.x;
  int idx = (d & 7) * Q + (d >> 3);
  int mt = idx % mtiles; int r = idx / mtiles;
  int nt = r & 15; r >>= 4;
  int tap = r % 3; int path = r / 3;

  const short* act = path ? actG : actM;
  const short* P   = path ? Pg : Pm;
  const int K3 = 3 * Cin;
  const int co0 = mt * 64;
  const int NT  = Cin >> 5;
  const int npl = path ? 2 : 3;

  const int tid = threadIdx.x;
  const int w = tid >> 6;
  const int l = tid & 63;

  __shared__ __align__(16) short Al[3][64 * 40];
  __shared__ __align__(16) short Bl[3][64 * 40];

  f32x16 acc[2] = {};
  v8s rA[3][2], rB[3][2];

  auto LOADA = [&](int t) {
    int ci0 = t << 5;
#pragma unroll
    for (int pl = 0; pl < 3; ++pl)
      if (pl < npl)
#pragma unroll
        for (int it = 0; it < 2; ++it) {
          int e = it * 128 + tid;
          int row = e >> 2, c8 = e & 3;
          rA[pl][it] = *(const v8s*)&P[(size_t)pl * Cout * K3 + (size_t)(co0 + row) * K3
                                       + tap * Cin + ci0 + c8 * 8];
        }
  };
  auto LOADB = [&](int t) {
    int ci0 = t << 5;
#pragma unroll
    for (int pl = 0; pl < 3; ++pl)
      if (pl < npl)
#pragma unroll
        for (int it = 0; it < 2; ++it) {
          int e = it * 128 + tid;
          int n = e >> 2, c8 = e & 3;
          int trow = n + tap - 1;
          v8s vv = {};
          if (trow >= 0 && trow < 64)
            vv = *(const v8s*)&act[(size_t)pl * psIn + ((size_t)(nt * 64 + trow)) * Cin
                                   + ci0 + c8 * 8];
          rB[pl][it] = vv;
        }
  };
  auto WRITE = [&]() {
#pragma unroll
    for (int pl = 0; pl < 3; ++pl)
      if (pl < npl)
#pragma unroll
        for (int it = 0; it < 2; ++it) {
          int e = it * 128 + tid;
          *(v8s*)&Al[pl][(e >> 2) * 40 + (e & 3) * 8] = rA[pl][it];
          *(v8s*)&Bl[pl][(e >> 2) * 40 + (e & 3) * 8] = rB[pl][it];
        }
  };

  LOADA(0); LOADB(0);
  WRITE();
  __syncthreads();

  for (int t = 0; t < NT; ++t) {
    if (t + 1 < NT) { LOADA(t + 1); LOADB(t + 1); }
    const int lr = l & 31, lh = (l >> 5) * 8;
#pragma unroll
    for (int kk = 0; kk < 2; ++kk) {
      const int ao = (w * 32 + lr) * 40 + kk * 16 + lh;
      v8s a0 = *(const v8s*)&Al[0][ao];
      v8s a1 = *(const v8s*)&Al[1][ao];
#pragma unroll
      for (int fn = 0; fn < 2; ++fn) {
        const int bo = (fn * 32 + lr) * 40 + kk * 16 + lh;
        v8s b0 = *(const v8s*)&Bl[0][bo];
        v8s b1 = *(const v8s*)&Bl[1][bo];
        acc[fn] = __builtin_amdgcn_mfma_f32_32x32x16_bf16(a0, b0, acc[fn], 0, 0, 0);
        acc[fn] = __builtin_amdgcn_mfma_f32_32x32x16_bf16(a0, b1, acc[fn], 0, 0, 0);
        acc[fn] = __builtin_amdgcn_mfma_f32_32x32x16_bf16(a1, b0, acc[fn], 0, 0, 0);
        if (path == 0) {
          v8s a2 = *(const v8s*)&Al[2][ao];
          v8s b2 = *(const v8s*)&Bl[2][bo];
          acc[fn] = __builtin_amdgcn_mfma_f32_32x32x16_bf16(a1, b1, acc[fn], 0, 0, 0);
          acc[fn] = __builtin_amdgcn_mfma_f32_32x32x16_bf16(a0, b2, acc[fn], 0, 0, 0);
          acc[fn] = __builtin_amdgcn_mfma_f32_32x32x16_bf16(a2, b0, acc[fn], 0, 0, 0);
        }
      }
    }
    __syncthreads();
    if (t + 1 < NT) { WRITE(); __syncthreads(); }
  }

  const int hi4 = 4 * (l >> 5);
  const size_t pbase = (size_t)(tap * 2 + path) * 1024;
#pragma unroll
  for (int fn = 0; fn < 2; ++fn) {
    int gn = nt * 64 + fn * 32 + (l & 31);
#pragma unroll
    for (int q4 = 0; q4 < 4; ++q4) {
      int co = co0 + w * 32 + q4 * 8 + hi4;
      float4 v = {acc[fn][q4 * 4 + 0], acc[fn][q4 * 4 + 1],
                  acc[fn][q4 * 4 + 2], acc[fn][q4 * 4 + 3]};
      *(float4*)&partial[(pbase + gn) * Cout + co] = v;
    }
  }
}

// -------------------------------------------------------------------------
// finalize (LRELU layers)
// -------------------------------------------------------------------------
__global__ void __launch_bounds__(256) finalize_lrelu(
    const float* __restrict__ partial,
    const float* __restrict__ BsM, const float* __restrict__ BsG,
    short* __restrict__ soutM, short* __restrict__ soutG)
{
  int e = blockIdx.x * 256 + threadIdx.x;
  int c4 = e & 127, gn = (e >> 7) & 1023, path = e >> 17;
  const float* Bs = path ? BsG : BsM;
  short* sout = path ? soutG : soutM;
  size_t base = ((size_t)(path) * 1024 + gn) * 512 + c4 * 4;
  const size_t TS = (size_t)2 * 1024 * 512;
  float4 s0 = *(const float4*)&partial[base];
  float4 s1 = *(const float4*)&partial[base + TS];
  float4 s2 = *(const float4*)&partial[base + 2 * TS];
  float4 bi = *(const float4*)&Bs[c4 * 4];
  const float* p0 = &s0.x; const float* p1 = &s1.x;
  const float* p2 = &s2.x; const float* pb = &bi.x;
  v4s h4, l4, q4v;
#pragma unroll
  for (int j = 0; j < 4; ++j) {
    float z = lrelu(p0[j] + p1[j] + p2[j] + pb[j]);
    short h, lo, qq; split3(z, h, lo, qq);
    h4[j] = h; l4[j] = lo; q4v[j] = qq;
  }
  size_t o = (size_t)gn * 512 + c4 * 4;
  *(v4s*)&sout[0 * 524288 + o] = h4;
  *(v4s*)&sout[1 * 524288 + o] = l4;
  *(v4s*)&sout[2 * 524288 + o] = q4v;
}

// -------------------------------------------------------------------------
// finalize (layer 5)
// -------------------------------------------------------------------------
__global__ void __launch_bounds__(256) finalize_l5(
    const float* __restrict__ partial,
    const float* __restrict__ fb, const float* __restrict__ lb,
    float* __restrict__ fsm, float* __restrict__ lsm)
{
  __shared__ float bandS[2][128];
  int tid = threadIdx.x;
  if (tid < 128) {
    double lg = log(551.25);
    double stop  = 20.0 * exp(lg * (double)tid / 127.0);
    double start = (tid == 0) ? 0.0 : 20.0 * exp(lg * (double)(tid - 1) / 127.0);
    bandS[0][tid] = (float)start;
    bandS[1][tid] = (float)(stop - start);
  }
  __syncthreads();

  int e = blockIdx.x * 256 + tid;
  int c4 = e & 31, gn = (e >> 5) & 1023, path = e >> 15;
  size_t base = ((size_t)(path) * 1024 + gn) * 128 + c4 * 4;
  const size_t TS = (size_t)2 * 1024 * 128;
  float4 s0 = *(const float4*)&partial[base];
  float4 s1 = *(const float4*)&partial[base + TS];
  float4 s2 = *(const float4*)&partial[base + 2 * TS];
  float4 bi = *(const float4*)&((path ? lb : fb)[c4 * 4]);
  const float* p0 = &s0.x; const float* p1 = &s1.x;
  const float* p2 = &s2.x; const float* pb = &bi.x;
  int b = gn >> 6, t = gn & 63;
#pragma unroll
  for (int j = 0; j < 4; ++j) {
    int co = c4 * 4 + j;
    float z = p0[j] + p1[j] + p2[j] + pb[j];
    if (path == 0)
      fsm[((size_t)(b * 128) + co) * 64 + t] = bandS[0][co] + bandS[1][co] / (1.f + expf(-z));
    else
      lsm[((size_t)(b * 128) + co) * 64 + t] = z * z;
  }
}

// -------------------------------------------------------------------------
// fold_all (vectorized)
// -------------------------------------------------------------------------
__global__ void __launch_bounds__(256) fold_all(
    const float* __restrict__ nw0, const float* __restrict__ nw1,
    const float* __restrict__ nw2, const float* __restrict__ nw3,
    const float* __restrict__ nlw,
    short* __restrict__ E1, short* __restrict__ E2,
    short* __restrict__ E3, short* __restrict__ E4,
    short* __restrict__ Pnl)
{
  int i = blockIdx.x * 256 + threadIdx.x;
  if (i >= 106496) {
    if (i >= 108544) return;
    int idx = i - 106496;
    int co = idx >> 6, ci = (idx & 63) * 8;
    v8s hv[3], lv[3];
#pragma unroll
    for (int j = 0; j < 8; ++j)
#pragma unroll
      for (int tap = 0; tap < 3; ++tap) {
        float v = (co < 17) ? nlw[((size_t)(co * 512 + ci + j)) * 3 + tap] : 0.f;
        short h = bf16rne(v);
        hv[tap][j] = h;
        lv[tap][j] = bf16rne(v - bf16tof(h));
      }
#pragma unroll
    for (int tap = 0; tap < 3; ++tap) {
      *(v8s*)&Pnl[(size_t)(0 * 32 + co) * 1536 + tap * 512 + ci] = hv[tap];
      *(v8s*)&Pnl[(size_t)(1 * 32 + co) * 1536 + tap * 512 + ci] = lv[tap];
    }
    return;
  }
  const float* W; short* Ag; int Cin; int idx;
  if (i < 8192)        { W = nw0; Ag = E1; Cin = 128; idx = i; }
  else if (i < 40960)  { W = nw1; Ag = E2; Cin = 512; idx = i - 8192; }
  else if (i < 73728)  { W = nw2; Ag = E3; Cin = 512; idx = i - 40960; }
  else                 { W = nw3; Ag = E4; Cin = 512; idx = i - 73728; }
  const int nci8 = Cin >> 3;
  int co = idx / nci8, ci = (idx - co * nci8) * 8;
  const float* wp = W + (size_t)(co * Cin + ci) * 7;
  const int K = Cin * 4;
  v8s he[4], le[4], ho[4], lo4[4];
#pragma unroll
  for (int j = 0; j < 8; ++j) {
    const float* w = wp + j * 7;
    float fe[4] = {w[0],        w[1] + w[2], w[3] + w[4], w[5] + w[6]};
    float fo[4] = {w[0] + w[1], w[2] + w[3], w[4] + w[5], w[6]};
#pragma unroll
    for (int q = 0; q < 4; ++q) {
      short h1 = bf16rne(fe[q]);
      he[q][j] = h1; le[q][j] = bf16rne(fe[q] - bf16tof(h1));
      short h2 = bf16rne(fo[q]);
      ho[q][j] = h2; lo4[q][j] = bf16rne(fo[q] - bf16tof(h2));
    }
  }
#pragma unroll
  for (int q = 0; q < 4; ++q) {
    size_t kbase = (size_t)q * Cin + ci;
    *(v8s*)&Ag[((size_t)(0 * 512 + co)) * K + kbase] = he[q];
    *(v8s*)&Ag[((size_t)(1 * 512 + co)) * K + kbase] = le[q];
    *(v8s*)&Ag[((size_t)(2 * 512 + co)) * K + kbase] = ho[q];
    *(v8s*)&Ag[((size_t)(3 * 512 + co)) * K + kbase] = lo4[q];
  }
}

// -------------------------------------------------------------------------
// Noise conv: ci-OUTER / q-INNER with shared B-slab (BNS+3 rows staged once
// per ci0; tap fragments read at row+q). B ds_writes and B HBM fetch drop 4x.
// 2-plane split-bf16 (hh,hl,lh), 32x32x16, T14 reg staging.
// -------------------------------------------------------------------------
template<int MF, int BNS, int CIN>
__global__ void __launch_bounds__(256, 2) conv_noise(
    const short* __restrict__ actIn, const short* __restrict__ Ag,
    const float* __restrict__ Bs, short* __restrict__ actOut,
    int Sin, int psIn, int psOut)
{
  constexpr int NF   = BNS / 64;
  constexpr int BM   = MF * 64;
  constexpr int AITS = BM / 32;
  constexpr int SLAB = BNS + 3;
  constexpr int BSL  = (2 * SLAB * 8 + 255) / 256;
  constexpr int K    = CIN * 4;
  constexpr int nci  = CIN / 64;
  const int mtiles = 512 / BM;
  const int stiles = Sin / BNS;
  const int nblk = mtiles * 2 * 16 * stiles;
  const int Q = nblk >> 3;
  int d = blockIdx.x;
  int idx = (d & 7) * Q + (d >> 3);
  int mt = idx % mtiles;
  int t1 = idx / mtiles;
  int par = t1 & 1;
  int rest = t1 >> 1;
  int st = rest % stiles;
  int b = rest / stiles;

  const int co0 = mt * BM;
  const int s0 = st * BNS;
  const int soff = par ? -1 : -2;

  const int tid = threadIdx.x;
  const int w = tid >> 6, wm = w & 1, wn = w >> 1;
  const int l = tid & 63;

  __shared__ __align__(16) short Al[2][BM * 72];
  __shared__ __align__(16) short Bl[2][SLAB * 72];

  f32x16 acc[MF][NF] = {};
  v8s rA[2][AITS];
  v8s rBS[BSL];

  auto LOADA = [&](int q, int ci0) {
#pragma unroll
    for (int pl = 0; pl < 2; ++pl)
#pragma unroll
      for (int it = 0; it < AITS; ++it) {
        int e = it * 256 + tid;
        int row = e >> 3, c8 = e & 7;
        rA[pl][it] = *(const v8s*)&Ag[((size_t)((par * 2 + pl) * 512 + co0 + row)) * K
                                      + q * CIN + ci0 + c8 * 8];
      }
  };
  auto WRITEA = [&]() {
#pragma unroll
    for (int pl = 0; pl < 2; ++pl)
#pragma unroll
      for (int it = 0; it < AITS; ++it) {
        int e = it * 256 + tid;
        *(v8s*)&Al[pl][(e >> 3) * 72 + (e & 7) * 8] = rA[pl][it];
      }
  };
  auto LOADBS = [&](int ci0) {
#pragma unroll
    for (int it = 0; it < BSL; ++it) {
      int e = it * 256 + tid;
      v8s vv = {};
      if (e < 2 * SLAB * 8) {
        int r3 = e >> 3, c8 = e & 7;
        int pl = r3 / SLAB, row = r3 - pl * SLAB;
        int srow = s0 + soff + row;
        if (srow >= 0 && srow < Sin)
          vv = *(const v8s*)&actIn[(size_t)pl * psIn + ((size_t)(b * Sin + srow)) * CIN
                                   + ci0 + c8 * 8];
      }
      rBS[it] = vv;
    }
  };
  auto WRITEBS = [&]() {
#pragma unroll
    for (int it = 0; it < BSL; ++it) {
      int e = it * 256 + tid;
      if (e < 2 * SLAB * 8) {
        int r3 = e >> 3, c8 = e & 7;
        int pl = r3 / SLAB, row = r3 - pl * SLAB;
        *(v8s*)&Bl[pl][row * 72 + c8 * 8] = rBS[it];
      }
    }
  };

  LOADBS(0); LOADA(0, 0);
  WRITEBS(); WRITEA();
  __syncthreads();

  for (int ci = 0; ci < nci; ++ci) {
    const int ci0 = ci << 6;
#pragma unroll
    for (int q = 0; q < 4; ++q) {
      const bool lastq = (q == 3);
      const bool lastall = lastq && (ci == nci - 1);
      if (!lastq)        LOADA(q + 1, ci0);
      else if (!lastall) { LOADBS(ci0 + 64); LOADA(0, ci0 + 64); }

      const int lr = l & 31, lh = (l >> 5) * 8;
#pragma unroll
      for (int kk = 0; kk < 4; ++kk) {
        v8s ah[MF], al[MF], bh[NF], bl[NF];
#pragma unroll
        for (int fm = 0; fm < MF; ++fm) {
          int ab = (wm * (MF * 32) + fm * 32 + lr) * 72 + kk * 16 + lh;
          ah[fm] = *(const v8s*)&Al[0][ab];
          al[fm] = *(const v8s*)&Al[1][ab];
        }
#pragma unroll
        for (int fn = 0; fn < NF; ++fn) {
          int bb = (wn * (BNS / 2) + fn * 32 + lr + q) * 72 + kk * 16 + lh;
          bh[fn] = *(const v8s*)&Bl[0][bb];
          bl[fn] = *(const v8s*)&Bl[1][bb];
        }
#pragma unroll
        for (int fm = 0; fm < MF; ++fm)
#pragma unroll
          for (int fn = 0; fn < NF; ++fn) {
            acc[fm][fn] = __builtin_amdgcn_mfma_f32_32x32x16_bf16(ah[fm], bh[fn], acc[fm][fn], 0, 0, 0);
            acc[fm][fn] = __builtin_amdgcn_mfma_f32_32x32x16_bf16(ah[fm], bl[fn], acc[fm][fn], 0, 0, 0);
            acc[fm][fn] = __builtin_amdgcn_mfma_f32_32x32x16_bf16(al[fm], bh[fn], acc[fm][fn], 0, 0, 0);
          }
      }
      __syncthreads();
      if (!lastall) {
        if (!lastq) WRITEA();
        else { WRITEBS(); WRITEA(); }
        __syncthreads();
      }
    }
  }

  // epilogue: 2-plane bf16 [pl][b][t=2s+par][512]
  const int hi4 = 4 * (l >> 5);
  const int T2 = 2 * Sin;
#pragma unroll
  for (int fm = 0; fm < MF; ++fm)
#pragma unroll
    for (int q4 = 0; q4 < 4; ++q4) {
      int co = co0 + wm * (MF * 32) + fm * 32 + q4 * 8 + hi4;
      float4 bia = *(const float4*)&Bs[co];
      const float* bp = &bia.x;
#pragma unroll
      for (int fn = 0; fn < NF; ++fn) {
        int s_l = wn * (BNS / 2) + fn * 32 + (l & 31);
        int t = 2 * (s0 + s_l) + par;
        v4s h4, l4;
#pragma unroll
        for (int j = 0; j < 4; ++j) {
          float z = lrelu(acc[fm][fn][q4 * 4 + j] + bp[j]);
          short h = bf16rne(z);
          h4[j] = h;
          l4[j] = bf16rne(z - bf16tof(h));
        }
        size_t o = ((size_t)(b * T2) + t) * 512 + co;
        *(v4s*)&actOut[0 * (size_t)psOut + o] = h4;
        *(v4s*)&actOut[1 * (size_t)psOut + o] = l4;
      }
    }
}

// -------------------------------------------------------------------------
// conv_nl (MFMA) fused with the noise-bank filter: computes mags = (conv)^2
// into LDS, then per-frame 17-bin DFT * mags -> inverse -> filt directly.
// Grid 256 = (b 16) x (16 t-tiles of 64 frames), 128 thr.
// -------------------------------------------------------------------------
#define NL_PS4 8388608   // l4act plane stride (shorts)

__global__ void __launch_bounds__(128) conv_nl_filter(
    const short* __restrict__ act, const short* __restrict__ Pnl,
    const float* __restrict__ Bs, const float* __restrict__ noise,
    float* __restrict__ filt)
{
  const int bid = blockIdx.x;
  const int b = bid >> 4, t0 = (bid & 15) << 6;
  const int tid = threadIdx.x;
  const int w = tid >> 6;
  const int l = tid & 63;

  __shared__ __align__(16) short Al[2 * 3 * 32 * 72];
  __shared__ __align__(16) short Bl[2 * 66 * 72];
  __shared__ float magS[64][20];
  __shared__ float ctS[32], stS[32];

  if (tid < 32) {
    double a = (double)tid * (3.14159265358979323846 / 16.0);
    ctS[tid] = (float)cos(a);
    stS[tid] = (float)sin(a);
  }

  f32x16 acc = {};

  for (int ci0 = 0; ci0 < 512; ci0 += 64) {
    for (int e = tid; e < 1536; e += 128) {
      int c8 = e & 7, row = e >> 3;
      int pl = row >= 96;
      int r2 = row - pl * 96;
      int tap = r2 >> 5, co = r2 & 31;
      v8s vv = *(const v8s*)&Pnl[(size_t)(pl * 32 + co) * 1536 + tap * 512 + ci0 + c8 * 8];
      *(v8s*)&Al[row * 72 + c8 * 8] = vv;
    }
    for (int e = tid; e < 1056; e += 128) {
      int c8 = e & 7, r = (e >> 3) % 66, pl = (e >> 3) / 66;
      int t = t0 + r - 1;
      v8s vv = {};
      if (t >= 0 && t < 1024)
        vv = *(const v8s*)&act[(size_t)pl * NL_PS4 + ((size_t)(b << 10) + t) * 512 + ci0 + c8 * 8];
      *(v8s*)&Bl[(pl * 66 + r) * 72 + c8 * 8] = vv;
    }
    __syncthreads();
    const int lr = l & 31, lh = (l >> 5) * 8;
#pragma unroll
    for (int kk = 0; kk < 4; ++kk)
#pragma unroll
      for (int tap = 0; tap < 3; ++tap) {
        v8s a_h = *(const v8s*)&Al[((0 * 3 + tap) * 32 + lr) * 72 + kk * 16 + lh];
        v8s a_l = *(const v8s*)&Al[((1 * 3 + tap) * 32 + lr) * 72 + kk * 16 + lh];
        int brow = w * 32 + lr + tap;
        v8s b_h = *(const v8s*)&Bl[(0 * 66 + brow) * 72 + kk * 16 + lh];
        v8s b_l = *(const v8s*)&Bl[(1 * 66 + brow) * 72 + kk * 16 + lh];
        acc = __builtin_amdgcn_mfma_f32_32x32x16_bf16(a_h, b_h, acc, 0, 0, 0);
        acc = __builtin_amdgcn_mfma_f32_32x32x16_bf16(a_h, b_l, acc, 0, 0, 0);
        acc = __builtin_amdgcn_mfma_f32_32x32x16_bf16(a_l, b_h, acc, 0, 0, 0);
      }
    __syncthreads();
  }

  // mags -> LDS
  const int t_loc = w * 32 + (l & 31);
  const int hi4 = 4 * (l >> 5);
#pragma unroll
  for (int q4 = 0; q4 < 4; ++q4)
#pragma unroll
    for (int j = 0; j < 4; ++j) {
      int co = q4 * 8 + hi4 + j;
      if (co < 17) {
        float z = acc[q4 * 4 + j] + Bs[co];
        magS[t_loc][co] = z * z;
      }
    }
  __syncthreads();

  // per-frame DFT filter (threads 0..63, frame i = t0 + tid)
  if (tid < 64) {
    int i = t0 + tid;
    float xv[32];
#pragma unroll
    for (int n = 0; n < 32; ++n) {
      int idx = i * 16 + n;
      xv[n] = (idx < 16384) ? noise[(size_t)b * 16384 + idx] : 0.f;
    }
    float Yr[17], Yi[17];
#pragma unroll
    for (int k = 0; k <= 16; ++k) {
      float xr = 0.f, xi = 0.f;
      int kk = 0;
#pragma unroll
      for (int n = 0; n < 32; ++n) {
        xr += xv[n] * ctS[kk];
        xi -= xv[n] * stS[kk];
        kk = (kk + k) & 31;
      }
      float m = magS[tid][k];
      Yr[k] = xr * m;
      Yi[k] = xi * m;
    }
    float* fo = filt + ((size_t)(b << 10) + i) * 32;
#pragma unroll
    for (int n = 0; n < 32; ++n) {
      float v = Yr[0] + ((n & 1) ? -Yr[16] : Yr[16]);
      int kk = n;
#pragma unroll
      for (int k = 1; k <= 15; ++k) {
        v += 2.f * (Yr[k] * ctS[kk] - Yi[k] * stS[kk]);
        kk = (kk + n) & 31;
      }
      fo[n] = v * (1.f / 32.f);
    }
  }
}

// -------------------------------------------------------------------------
// Oscillator bank (3-point lerp endpoints + f64 chunk base + f32 Kahan).
// -------------------------------------------------------------------------
static __device__ __forceinline__ int clamp64(int i) { return i < 0 ? 0 : (i > 63 ? 63 : i); }

__global__ void __launch_bounds__(256) osc_phase(
    const float* __restrict__ fsm, double* __restrict__ phaseBase)
{
  const int o = blockIdx.x, b = blockIdx.y;
  const float* frow = fsm + (size_t)(b * 128 + o) * 64;
  const int c = threadIdx.x;

  const float ic0 = ((float)(c * 64) - 127.5f) * (1.0f / 256.0f);
  const int ilo = (int)floorf(ic0);
  float f0 = frow[clamp64(ilo)], f1 = frow[clamp64(ilo + 1)], f2 = frow[clamp64(ilo + 2)];

  double local = 0.0;
#pragma unroll 8
  for (int j = 0; j < 64; ++j) {
    float ic = ic0 + (float)j * (1.0f / 256.0f);
    float fl = floorf(ic);
    float w  = ic - fl;
    bool hi = ((int)fl) > ilo;
    float fa = hi ? f1 : f0;
    float fb = hi ? f2 : f1;
    float f = fa * (1.f - w) + fb * w;
    f = fminf(fmaxf(f, 20.f), 11025.f);
    local += (double)f;
  }
  local *= (1.0 / 22050.0);

  __shared__ double ps[256];
  ps[c] = local;
  __syncthreads();
  for (int off = 1; off < 256; off <<= 1) {
    double v = (c >= off) ? ps[c - off] : 0.0;
    __syncthreads();
    ps[c] += v;
    __syncthreads();
  }
  phaseBase[(size_t)(b * 128 + o) * 256 + c] = ps[c] - local;
}

__global__ void __launch_bounds__(128) osc_sum(
    const float* __restrict__ fsm, const float* __restrict__ lsm,
    const double* __restrict__ phaseBase, const float* __restrict__ filt,
    float* __restrict__ out)
{
  const int c = blockIdx.x, b = blockIdx.y;
  const int tid = threadIdx.x;
  __shared__ float contrib[128][65];
  __shared__ float part[2][64];
  const int o = tid;
  const float* frow = fsm + (size_t)(b * 128 + o) * 64;
  const float* arow = lsm + (size_t)(b * 128 + o) * 64;

  double pb = phaseBase[(size_t)(b * 128 + o) * 256 + c];
  float fb0 = (float)(pb - floor(pb));

  const float ic0 = ((float)(c * 64) - 127.5f) * (1.0f / 256.0f);
  const int ilo = (int)floorf(ic0);
  float f0 = frow[clamp64(ilo)], f1 = frow[clamp64(ilo + 1)], f2 = frow[clamp64(ilo + 2)];
  float a0 = arow[clamp64(ilo)], a1 = arow[clamp64(ilo + 1)], a2 = arow[clamp64(ilo + 2)];

  float rel = 0.f, comp = 0.f;
#pragma unroll 8
  for (int j = 0; j < 64; ++j) {
    float ic = ic0 + (float)j * (1.0f / 256.0f);
    float fl = floorf(ic);
    float w  = ic - fl;
    bool hi = ((int)fl) > ilo;
    float fa = hi ? f1 : f0;
    float fb = hi ? f2 : f1;
    float f = fa * (1.f - w) + fb * w;
    f = fminf(fmaxf(f, 20.f), 11025.f);
    float y = f * (1.0f / 22050.0f) - comp;
    float t = rel + y;
    comp = (t - rel) - y;
    rel = t;
    float tot = fb0 + rel;
    float frac = tot - floorf(tot);
    float s = sinpif(2.f * frac);
    float aa = hi ? a1 : a0;
    float ab = hi ? a2 : a1;
    float am = aa * (1.f - w) + ab * w;
    contrib[o][j] = s * am;
  }
  __syncthreads();
  int half = tid >> 6, tl = tid & 63;
  float sum = 0.f;
  for (int oo = 0; oo < 64; ++oo) sum += contrib[half * 64 + oo][tl];
  part[half][tl] = sum;
  __syncthreads();
  if (tid < 64) {
    int t = c * 64 + tid;
    float v = part[0][tid] + part[1][tid];
    int i0 = t >> 4, r = t & 15;
    v += filt[((size_t)(b << 10) + i0) * 32 + r];
    if (i0 > 0) v += filt[((size_t)(b << 10) + i0 - 1) * 32 + 16 + r];
    out[(size_t)b * 16384 + t] = v;
  }
}

// -------------------------------------------------------------------------
extern "C" void kernel_launch(void* const* d_in, const int* in_sizes, int n_in,
                              void* d_out, int out_size, void* d_ws, size_t ws_size,
                              hipStream_t stream)
{
  (void)in_sizes; (void)n_in; (void)out_size; (void)ws_size;

  const float* x     = (const float*)d_in[0];
  const float* noise = (const float*)d_in[1];
  const float* mw0 = (const float*)d_in[2];  const float* mb0 = (const float*)d_in[3];
  const float* mw1 = (const float*)d_in[4];  const float* mb1 = (const float*)d_in[5];
  const float* mw2 = (const float*)d_in[6];  const float* mb2 = (const float*)d_in[7];
  const float* mw3 = (const float*)d_in[8];  const float* mb3 = (const float*)d_in[9];
  const float* fw  = (const float*)d_in[10]; const float* fb  = (const float*)d_in[11];
  const float* gw0 = (const float*)d_in[12]; const float* gb0 = (const float*)d_in[13];
  const float* gw1 = (const float*)d_in[14]; const float* gb1 = (const float*)d_in[15];
  const float* gw2 = (const float*)d_in[16]; const float* gb2 = (const float*)d_in[17];
  const float* gw3 = (const float*)d_in[18]; const float* gb3 = (const float*)d_in[19];
  const float* lw  = (const float*)d_in[20]; const float* lb  = (const float*)d_in[21];
  const float* nw0 = (const float*)d_in[22]; const float* nb0 = (const float*)d_in[23];
  const float* nw1 = (const float*)d_in[24]; const float* nb1 = (const float*)d_in[25];
  const float* nw2 = (const float*)d_in[26]; const float* nb2 = (const float*)d_in[27];
  const float* nw3 = (const float*)d_in[28]; const float* nb3 = (const float*)d_in[29];
  const float* nlw = (const float*)d_in[30]; const float* nlb = (const float*)d_in[31];

  // ---- workspace (BYTE offsets; high-water 60,751,872 B < 63 MB cap) ----
  char* W8 = (char*)d_ws;
  short* mP  = (short*)(W8 + 0);
  short* gP  = (short*)(W8 + 16515072);
  short* hm0 = (short*)(W8 + 33030144);
  short* hm1 = (short*)(W8 + 36175872);
  short* hg0 = (short*)(W8 + 39321600);
  short* hg1 = (short*)(W8 + 42467328);
  float* partial = (float*)(W8 + 45613056);  // 12,582,912 B
  short* xm3 = (short*)(W8 + 58720256);
  float* fsm = (float*)(W8 + 59506688);
  float* lsm = (float*)(W8 + 60030976);
  short* Pnl = (short*)(W8 + 60555264);    // 196,608 B

  short* E4  = (short*)(W8 + 0);           // 8,388,608 B
  short* E3  = (short*)(W8 + 33554432);    // 8,388,608 B
  short* E2  = (short*)(W8 + 41943040);    // 8,388,608 B
  short* E1  = (short*)(W8 + 50331648);    // 2,097,152 B
  short* l1out = (short*)(W8 + 52428800);  // 4,194,304 B
  short* l2out = (short*)(W8 + 25165824);  // 8,388,608 B
  short* l3out = (short*)(W8 + 8388608);   // 16,777,216 B
  short* l4act = (short*)(W8 + 25165824);  // 33,554,432 B

  float* filt = (float*)(W8 + 1114112);    // 2,097,152 B
  double* phaseBase = (double*)(W8 + 4194304);  // 4,194,304 B

  float* out = (float*)d_out;

  const int PS_X = 131072;   // xm3 plane stride (shorts)
  const int PS_H = 524288;   // m/g act plane stride (shorts)

  // ---- prep ----
  prep_acts<<<512, 256, 0, stream>>>(x, xm3);
  prep_panels<<<896, 256, 0, stream>>>(mw0, mw1, mw2, mw3, fw,
                                       gw0, gw1, gw2, gw3, lw, mP, gP);

  // ---- m/g paths: tap-split MFMA + finalize ----
  conv_path_tap<<<768, 128, 0, stream>>>(xm3, xm3, mP + 0, gP + 0, partial, 128, 512, PS_X);
  finalize_lrelu<<<1024, 256, 0, stream>>>(partial, mb0, gb0, hm0, hg0);
  conv_path_tap<<<768, 128, 0, stream>>>(hm0, hg0, mP + 589824, gP + 589824, partial, 512, 512, PS_H);
  finalize_lrelu<<<1024, 256, 0, stream>>>(partial, mb1, gb1, hm1, hg1);
  conv_path_tap<<<768, 128, 0, stream>>>(hm1, hg1, mP + 2949120, gP + 2949120, partial, 512, 512, PS_H);
  finalize_lrelu<<<1024, 256, 0, stream>>>(partial, mb2, gb2, hm0, hg0);
  conv_path_tap<<<768, 128, 0, stream>>>(hm0, hg0, mP + 5308416, gP + 5308416, partial, 512, 512, PS_H);
  finalize_lrelu<<<1024, 256, 0, stream>>>(partial, mb3, gb3, hm1, hg1);
  conv_path_tap<<<192, 128, 0, stream>>>(hm1, hg1, mP + 7667712, gP + 7667712, partial, 512, 128, PS_H);
  finalize_l5<<<256, 256, 0, stream>>>(partial, fb, lb, fsm, lsm);

  // ---- noise path ----
  fold_all<<<424, 256, 0, stream>>>(nw0, nw1, nw2, nw3, nlw, E1, E2, E3, E4, Pnl);
  conv_noise<1, 64, 128><<<256, 256, 0, stream>>>(xm3, E1, nb0, l1out, 64, PS_X, 1048576);
  conv_noise<2, 64, 512><<<256, 256, 0, stream>>>(l1out, E2, nb1, l2out, 128, 1048576, 2097152);
  conv_noise<2, 128, 512><<<256, 256, 0, stream>>>(l2out, E3, nb2, l3out, 256, 2097152, 4194304);
  conv_noise<2, 128, 512><<<512, 256, 0, stream>>>(l3out, E4, nb3, l4act, 512, 4194304, 8388608);

  // conv 512->17 + squared + per-frame DFT filter, fused
  conv_nl_filter<<<256, 128, 0, stream>>>(l4act, Pnl, nlb, noise, filt);

  // ---- oscillator bank + final sum ----
  osc_phase<<<dim3(128, 16), 256, 0, stream>>>(fsm, phaseBase);
  osc_sum<<<dim3(256, 16), 128, 0, stream>>>(fsm, lsm, phaseBase, filt, out);
}

// Round 13
// 507.722 us; speedup vs baseline: 1.0926x; 1.0142x over previous
//
#include <hip/hip_runtime.h>
#include <math.h>

#define ACT_LRELU  0
#define ACT_SIGMAP 1
#define ACT_SQUARE 2

typedef __attribute__((ext_vector_type(8))) short v8s;
typedef __attribute__((ext_vector_type(4))) short v4s;
typedef __attribute__((ext_vector_type(16))) float f32x16;

static __device__ __forceinline__ float lrelu(float x) { return x >= 0.f ? x : 0.2f * x; }

static __device__ __forceinline__ short bf16rne(float x) {
  unsigned u = __float_as_uint(x);
  unsigned r = (u + 0x7FFFu + ((u >> 16) & 1u)) >> 16;
  return (short)r;
}
static __device__ __forceinline__ float bf16tof(short h) {
  return __uint_as_float(((unsigned)(unsigned short)h) << 16);
}
static __device__ __forceinline__ void split3(float v, short& h, short& l, short& q) {
  h = bf16rne(v); float r1 = v - bf16tof(h);
  l = bf16rne(r1); float r2 = r1 - bf16tof(l);
  q = bf16rne(r2);
}

// -------------------------------------------------------------------------
// prep_mg: acts + m/g panels in one launch (blocks range-dispatch).
// NOTE: must NOT write any noise-panel region — those alias phase-A memory
// and are only dead after the m/g conv chain (round-11 lesson).
//  [0,512)      prep_acts:   x -> xm3 3-plane bf16 [pl][b][t][ci]
//  [512,1408)   prep_panels: m/g weights -> 3-plane tap-major panels
// -------------------------------------------------------------------------
__global__ void __launch_bounds__(256) prep_mg(
    const float* __restrict__ x, short* __restrict__ xm3,
    const float* mw0, const float* mw1, const float* mw2, const float* mw3, const float* fw,
    const float* gw0, const float* gw1, const float* gw2, const float* gw3, const float* lw,
    short* __restrict__ mP, short* __restrict__ gP)
{
  const int blk = blockIdx.x;
  const int tid = threadIdx.x;

  if (blk < 512) {
    int e = blk * 256 + tid;
    if (e >= 131072) return;
    int b = e >> 13, rem = e & 8191, t = rem >> 7, ci = rem & 127;
    float v = x[((size_t)(b * 128) + ci) * 64 + t];
    short h, l, q; split3(v, h, l, q);
    size_t o = ((size_t)(b * 64) + t) * 128 + ci;
    xm3[0 * 131072 + o] = h;
    xm3[1 * 131072 + o] = l;
    xm3[2 * 131072 + o] = q;
    return;
  }

  // ---- prep_panels (vectorized: 8 ci per thread) ----
  int i = (blk - 512) * 256 + tid;
  const int PER = 114688;
  if (i >= 2 * PER) return;
  int path = i >= PER ? 1 : 0;
  int r = i - path * PER;
  int Cin, Cout; size_t poff;
  const float* W;
  {
    int layer;
    if (r < 8192)        { layer = 0;              Cin = 128; Cout = 512; poff = 0; }
    else if (r < 40960)  { layer = 1; r -= 8192;   Cin = 512; Cout = 512; poff = 589824; }
    else if (r < 73728)  { layer = 2; r -= 40960;  Cin = 512; Cout = 512; poff = 2949120; }
    else if (r < 106496) { layer = 3; r -= 73728;  Cin = 512; Cout = 512; poff = 5308416; }
    else                 { layer = 4; r -= 106496; Cin = 512; Cout = 128; poff = 7667712; }
    const float* Wm[5] = {mw0, mw1, mw2, mw3, fw};
    const float* Wg[5] = {gw0, gw1, gw2, gw3, lw};
    W = path ? Wg[layer] : Wm[layer];
  }
  short* P = (path ? gP : mP) + poff;
  const int nci8 = Cin >> 3;
  int co = r / nci8, ci = (r - co * nci8) * 8;
  const int K3 = 3 * Cin;
  const float* wp = W + (size_t)(co * Cin + ci) * 3;
  v8s hv[3], lv[3], qv[3];
#pragma unroll
  for (int j = 0; j < 8; ++j)
#pragma unroll
    for (int tap = 0; tap < 3; ++tap) {
      short h, l, q; split3(wp[j * 3 + tap], h, l, q);
      hv[tap][j] = h; lv[tap][j] = l; qv[tap][j] = q;
    }
#pragma unroll
  for (int tap = 0; tap < 3; ++tap) {
    size_t base = (size_t)co * K3 + tap * Cin + ci;
    *(v8s*)&P[(size_t)0 * Cout * K3 + base] = hv[tap];
    *(v8s*)&P[(size_t)1 * Cout * K3 + base] = lv[tap];
    *(v8s*)&P[(size_t)2 * Cout * K3 + base] = qv[tap];
  }
}

// -------------------------------------------------------------------------
// fold_all (vectorized): noise weights -> folded parity hi/lo panels + Pnl.
// MUST run after the m/g conv chain (E-panels alias mP/hm/hg regions).
// -------------------------------------------------------------------------
__global__ void __launch_bounds__(256) fold_all(
    const float* __restrict__ nw0, const float* __restrict__ nw1,
    const float* __restrict__ nw2, const float* __restrict__ nw3,
    const float* __restrict__ nlw,
    short* __restrict__ E1, short* __restrict__ E2,
    short* __restrict__ E3, short* __restrict__ E4,
    short* __restrict__ Pnl)
{
  int i = blockIdx.x * 256 + threadIdx.x;
  if (i >= 106496) {
    if (i >= 108544) return;
    int idx = i - 106496;
    int co = idx >> 6, ci = (idx & 63) * 8;
    v8s hv[3], lv[3];
#pragma unroll
    for (int j = 0; j < 8; ++j)
#pragma unroll
      for (int tap = 0; tap < 3; ++tap) {
        float v = (co < 17) ? nlw[((size_t)(co * 512 + ci + j)) * 3 + tap] : 0.f;
        short h = bf16rne(v);
        hv[tap][j] = h;
        lv[tap][j] = bf16rne(v - bf16tof(h));
      }
#pragma unroll
    for (int tap = 0; tap < 3; ++tap) {
      *(v8s*)&Pnl[(size_t)(0 * 32 + co) * 1536 + tap * 512 + ci] = hv[tap];
      *(v8s*)&Pnl[(size_t)(1 * 32 + co) * 1536 + tap * 512 + ci] = lv[tap];
    }
    return;
  }
  const float* W; short* Ag; int Cin; int idx;
  if (i < 8192)        { W = nw0; Ag = E1; Cin = 128; idx = i; }
  else if (i < 40960)  { W = nw1; Ag = E2; Cin = 512; idx = i - 8192; }
  else if (i < 73728)  { W = nw2; Ag = E3; Cin = 512; idx = i - 40960; }
  else                 { W = nw3; Ag = E4; Cin = 512; idx = i - 73728; }
  const int nci8 = Cin >> 3;
  int co = idx / nci8, ci = (idx - co * nci8) * 8;
  const float* wp = W + (size_t)(co * Cin + ci) * 7;
  const int K = Cin * 4;
  v8s he[4], le[4], ho[4], lo4[4];
#pragma unroll
  for (int j = 0; j < 8; ++j) {
    const float* w = wp + j * 7;
    float fe[4] = {w[0],        w[1] + w[2], w[3] + w[4], w[5] + w[6]};
    float fo[4] = {w[0] + w[1], w[2] + w[3], w[4] + w[5], w[6]};
#pragma unroll
    for (int q = 0; q < 4; ++q) {
      short h1 = bf16rne(fe[q]);
      he[q][j] = h1; le[q][j] = bf16rne(fe[q] - bf16tof(h1));
      short h2 = bf16rne(fo[q]);
      ho[q][j] = h2; lo4[q][j] = bf16rne(fo[q] - bf16tof(h2));
    }
  }
#pragma unroll
  for (int q = 0; q < 4; ++q) {
    size_t kbase = (size_t)q * Cin + ci;
    *(v8s*)&Ag[((size_t)(0 * 512 + co)) * K + kbase] = he[q];
    *(v8s*)&Ag[((size_t)(1 * 512 + co)) * K + kbase] = le[q];
    *(v8s*)&Ag[((size_t)(2 * 512 + co)) * K + kbase] = ho[q];
    *(v8s*)&Ag[((size_t)(3 * 512 + co)) * K + kbase] = lo4[q];
  }
}

// -------------------------------------------------------------------------
// m/g path conv: 3-plane split-bf16 MFMA GEMM, 32x32x16, ~fp32 precision,
// T14 async staging. Single kernel per layer (activation + split fused).
// -------------------------------------------------------------------------
__global__ void __launch_bounds__(256, 2) conv_path(
    const short* __restrict__ actM, const short* __restrict__ actG,
    const short* __restrict__ Pm, const short* __restrict__ Pg,
    const float* __restrict__ BsM, const float* __restrict__ BsG,
    float* __restrict__ foutM, float* __restrict__ foutG,
    short* __restrict__ soutM, short* __restrict__ soutG,
    int Cin, int Cout, int psIn, int psOut, int actMk, int actGk)
{
  const int mtiles = Cout >> 6;
  const int nblk = 2 * mtiles * 16;
  const int Q = nblk >> 3;
  int d = blockIdx.x;
  int idx = (d & 7) * Q + (d >> 3);
  int mt = idx % mtiles;
  int tmp = idx / mtiles;
  int nt = tmp & 15;
  int path = tmp >> 4;

  const short* act = path ? actG : actM;
  const short* P   = path ? Pg : Pm;
  const float* Bs  = path ? BsG : BsM;
  float* fout      = path ? foutG : foutM;
  short* sout      = path ? soutG : soutM;
  const int actk   = path ? actGk : actMk;

  const int K3 = 3 * Cin;
  const int co0 = mt * 64;
  const int n0  = nt * 64;
  const int nci = Cin >> 6;
  const int NT  = 3 * nci;

  const int tid = threadIdx.x;
  const int w = tid >> 6, wm = w & 1, wn = w >> 1;
  const int l = tid & 63;

  __shared__ __align__(16) short Al[3][64 * 72];
  __shared__ __align__(16) short Bl[3][64 * 72];
  __shared__ float bandS[2][128];

  if (actk == ACT_SIGMAP && tid < 128) {
    double lg = log(551.25);
    double stop  = 20.0 * exp(lg * (double)tid / 127.0);
    double start = (tid == 0) ? 0.0 : 20.0 * exp(lg * (double)(tid - 1) / 127.0);
    bandS[0][tid] = (float)start;
    bandS[1][tid] = (float)(stop - start);
  }

  f32x16 acc = {};
  v8s rA[3][2], rB[3][2];

  auto LOADA = [&](int t) {
    int tap = t / nci, ci0 = (t % nci) << 6;
#pragma unroll
    for (int pl = 0; pl < 3; ++pl)
#pragma unroll
      for (int it = 0; it < 2; ++it) {
        int e = it * 256 + tid;
        int row = e >> 3, c8 = e & 7;
        rA[pl][it] = *(const v8s*)&P[(size_t)pl * Cout * K3 + (size_t)(co0 + row) * K3
                                     + tap * Cin + ci0 + c8 * 8];
      }
  };
  auto LOADB = [&](int t) {
    int tap = t / nci, ci0 = (t % nci) << 6;
#pragma unroll
    for (int pl = 0; pl < 3; ++pl)
#pragma unroll
      for (int it = 0; it < 2; ++it) {
        int e = it * 256 + tid;
        int n = e >> 3, c8 = e & 7;
        int gn = n0 + n, bb = gn >> 6, trow = (gn & 63) + tap - 1;
        v8s vv = {};
        if (trow >= 0 && trow < 64)
          vv = *(const v8s*)&act[(size_t)pl * psIn + ((size_t)(bb * 64 + trow)) * Cin
                                 + ci0 + c8 * 8];
        rB[pl][it] = vv;
      }
  };
  auto WRITE = [&]() {
#pragma unroll
    for (int pl = 0; pl < 3; ++pl)
#pragma unroll
      for (int it = 0; it < 2; ++it) {
        int e = it * 256 + tid;
        int row = e >> 3, c8 = e & 7;
        *(v8s*)&Al[pl][row * 72 + c8 * 8] = rA[pl][it];
        *(v8s*)&Bl[pl][row * 72 + c8 * 8] = rB[pl][it];
      }
  };

  LOADA(0); LOADB(0);
  WRITE();
  __syncthreads();

  for (int t = 0; t < NT; ++t) {
    if (t + 1 < NT) { LOADA(t + 1); LOADB(t + 1); }
    const int abase = (wm * 32 + (l & 31)) * 72 + (l >> 5) * 8;
    const int bbase = (wn * 32 + (l & 31)) * 72 + (l >> 5) * 8;
#pragma unroll
    for (int kk = 0; kk < 4; ++kk) {
      v8s a0 = *(const v8s*)&Al[0][abase + kk * 16];
      v8s a1 = *(const v8s*)&Al[1][abase + kk * 16];
      v8s a2 = *(const v8s*)&Al[2][abase + kk * 16];
      v8s b0 = *(const v8s*)&Bl[0][bbase + kk * 16];
      v8s b1 = *(const v8s*)&Bl[1][bbase + kk * 16];
      v8s b2 = *(const v8s*)&Bl[2][bbase + kk * 16];
      acc = __builtin_amdgcn_mfma_f32_32x32x16_bf16(a0, b0, acc, 0, 0, 0);
      acc = __builtin_amdgcn_mfma_f32_32x32x16_bf16(a0, b1, acc, 0, 0, 0);
      acc = __builtin_amdgcn_mfma_f32_32x32x16_bf16(a1, b0, acc, 0, 0, 0);
      acc = __builtin_amdgcn_mfma_f32_32x32x16_bf16(a1, b1, acc, 0, 0, 0);
      acc = __builtin_amdgcn_mfma_f32_32x32x16_bf16(a0, b2, acc, 0, 0, 0);
      acc = __builtin_amdgcn_mfma_f32_32x32x16_bf16(a2, b0, acc, 0, 0, 0);
    }
    __syncthreads();
    if (t + 1 < NT) { WRITE(); __syncthreads(); }
  }

  // epilogue: C/D layout col=lane&31, row=(r&3)+8*(r>>2)+4*(lane>>5)
  const int ncol = wn * 32 + (l & 31);
  const int gn = n0 + ncol, bb = gn >> 6, t = gn & 63;
  const int hi4 = 4 * (l >> 5);
#pragma unroll
  for (int q4 = 0; q4 < 4; ++q4) {
    int co = co0 + wm * 32 + q4 * 8 + hi4;
    float4 bia = *(const float4*)&Bs[co];
    const float* bp = &bia.x;
    float z[4];
#pragma unroll
    for (int j = 0; j < 4; ++j) z[j] = acc[q4 * 4 + j] + bp[j];
    if (actk == ACT_LRELU) {
      v4s h4, l4, q4v;
#pragma unroll
      for (int j = 0; j < 4; ++j) {
        float zz = lrelu(z[j]);
        short h, lo, qq; split3(zz, h, lo, qq);
        h4[j] = h; l4[j] = lo; q4v[j] = qq;
      }
      size_t o = ((size_t)(bb * 64) + t) * Cout + co;
      *(v4s*)&sout[0 * (size_t)psOut + o] = h4;
      *(v4s*)&sout[1 * (size_t)psOut + o] = l4;
      *(v4s*)&sout[2 * (size_t)psOut + o] = q4v;
    } else if (actk == ACT_SIGMAP) {
#pragma unroll
      for (int j = 0; j < 4; ++j) {
        float f = bandS[0][co + j] + bandS[1][co + j] / (1.f + expf(-z[j]));
        fout[((size_t)(bb * 128) + co + j) * 64 + t] = f;
      }
    } else {
#pragma unroll
      for (int j = 0; j < 4; ++j)
        fout[((size_t)(bb * 128) + co + j) * 64 + t] = z[j] * z[j];
    }
  }
}

// -------------------------------------------------------------------------
// Noise conv: ci-OUTER / q-INNER with shared B-slab (B staged once per ci0).
// 2-plane split-bf16 (hh,hl,lh), 32x32x16, T14 reg staging.
// -------------------------------------------------------------------------
template<int MF, int BNS, int CIN>
__global__ void __launch_bounds__(256, 2) conv_noise(
    const short* __restrict__ actIn, const short* __restrict__ Ag,
    const float* __restrict__ Bs, short* __restrict__ actOut,
    int Sin, int psIn, int psOut)
{
  constexpr int NF   = BNS / 64;
  constexpr int BM   = MF * 64;
  constexpr int AITS = BM / 32;
  constexpr int SLAB = BNS + 3;
  constexpr int BSL  = (2 * SLAB * 8 + 255) / 256;
  constexpr int K    = CIN * 4;
  constexpr int nci  = CIN / 64;
  const int mtiles = 512 / BM;
  const int stiles = Sin / BNS;
  const int nblk = mtiles * 2 * 16 * stiles;
  const int Q = nblk >> 3;
  int d = blockIdx.x;
  int idx = (d & 7) * Q + (d >> 3);
  int mt = idx % mtiles;
  int t1 = idx / mtiles;
  int par = t1 & 1;
  int rest = t1 >> 1;
  int st = rest % stiles;
  int b = rest / stiles;

  const int co0 = mt * BM;
  const int s0 = st * BNS;
  const int soff = par ? -1 : -2;

  const int tid = threadIdx.x;
  const int w = tid >> 6, wm = w & 1, wn = w >> 1;
  const int l = tid & 63;

  __shared__ __align__(16) short Al[2][BM * 72];
  __shared__ __align__(16) short Bl[2][SLAB * 72];

  f32x16 acc[MF][NF] = {};
  v8s rA[2][AITS];
  v8s rBS[BSL];

  auto LOADA = [&](int q, int ci0) {
#pragma unroll
    for (int pl = 0; pl < 2; ++pl)
#pragma unroll
      for (int it = 0; it < AITS; ++it) {
        int e = it * 256 + tid;
        int row = e >> 3, c8 = e & 7;
        rA[pl][it] = *(const v8s*)&Ag[((size_t)((par * 2 + pl) * 512 + co0 + row)) * K
                                      + q * CIN + ci0 + c8 * 8];
      }
  };
  auto WRITEA = [&]() {
#pragma unroll
    for (int pl = 0; pl < 2; ++pl)
#pragma unroll
      for (int it = 0; it < AITS; ++it) {
        int e = it * 256 + tid;
        *(v8s*)&Al[pl][(e >> 3) * 72 + (e & 7) * 8] = rA[pl][it];
      }
  };
  auto LOADBS = [&](int ci0) {
#pragma unroll
    for (int it = 0; it < BSL; ++it) {
      int e = it * 256 + tid;
      v8s vv = {};
      if (e < 2 * SLAB * 8) {
        int r3 = e >> 3, c8 = e & 7;
        int pl = r3 / SLAB, row = r3 - pl * SLAB;
        int srow = s0 + soff + row;
        if (srow >= 0 && srow < Sin)
          vv = *(const v8s*)&actIn[(size_t)pl * psIn + ((size_t)(b * Sin + srow)) * CIN
                                   + ci0 + c8 * 8];
      }
      rBS[it] = vv;
    }
  };
  auto WRITEBS = [&]() {
#pragma unroll
    for (int it = 0; it < BSL; ++it) {
      int e = it * 256 + tid;
      if (e < 2 * SLAB * 8) {
        int r3 = e >> 3, c8 = e & 7;
        int pl = r3 / SLAB, row = r3 - pl * SLAB;
        *(v8s*)&Bl[pl][row * 72 + c8 * 8] = rBS[it];
      }
    }
  };

  LOADBS(0); LOADA(0, 0);
  WRITEBS(); WRITEA();
  __syncthreads();

  for (int ci = 0; ci < nci; ++ci) {
    const int ci0 = ci << 6;
#pragma unroll
    for (int q = 0; q < 4; ++q) {
      const bool lastq = (q == 3);
      const bool lastall = lastq && (ci == nci - 1);
      if (!lastq)        LOADA(q + 1, ci0);
      else if (!lastall) { LOADBS(ci0 + 64); LOADA(0, ci0 + 64); }

      const int lr = l & 31, lh = (l >> 5) * 8;
#pragma unroll
      for (int kk = 0; kk < 4; ++kk) {
        v8s ah[MF], al[MF], bh[NF], bl[NF];
#pragma unroll
        for (int fm = 0; fm < MF; ++fm) {
          int ab = (wm * (MF * 32) + fm * 32 + lr) * 72 + kk * 16 + lh;
          ah[fm] = *(const v8s*)&Al[0][ab];
          al[fm] = *(const v8s*)&Al[1][ab];
        }
#pragma unroll
        for (int fn = 0; fn < NF; ++fn) {
          int bb = (wn * (BNS / 2) + fn * 32 + lr + q) * 72 + kk * 16 + lh;
          bh[fn] = *(const v8s*)&Bl[0][bb];
          bl[fn] = *(const v8s*)&Bl[1][bb];
        }
#pragma unroll
        for (int fm = 0; fm < MF; ++fm)
#pragma unroll
          for (int fn = 0; fn < NF; ++fn) {
            acc[fm][fn] = __builtin_amdgcn_mfma_f32_32x32x16_bf16(ah[fm], bh[fn], acc[fm][fn], 0, 0, 0);
            acc[fm][fn] = __builtin_amdgcn_mfma_f32_32x32x16_bf16(ah[fm], bl[fn], acc[fm][fn], 0, 0, 0);
            acc[fm][fn] = __builtin_amdgcn_mfma_f32_32x32x16_bf16(al[fm], bh[fn], acc[fm][fn], 0, 0, 0);
          }
      }
      __syncthreads();
      if (!lastall) {
        if (!lastq) WRITEA();
        else { WRITEBS(); WRITEA(); }
        __syncthreads();
      }
    }
  }

  // epilogue: 2-plane bf16 [pl][b][t=2s+par][512]
  const int hi4 = 4 * (l >> 5);
  const int T2 = 2 * Sin;
#pragma unroll
  for (int fm = 0; fm < MF; ++fm)
#pragma unroll
    for (int q4 = 0; q4 < 4; ++q4) {
      int co = co0 + wm * (MF * 32) + fm * 32 + q4 * 8 + hi4;
      float4 bia = *(const float4*)&Bs[co];
      const float* bp = &bia.x;
#pragma unroll
      for (int fn = 0; fn < NF; ++fn) {
        int s_l = wn * (BNS / 2) + fn * 32 + (l & 31);
        int t = 2 * (s0 + s_l) + par;
        v4s h4, l4;
#pragma unroll
        for (int j = 0; j < 4; ++j) {
          float z = lrelu(acc[fm][fn][q4 * 4 + j] + bp[j]);
          short h = bf16rne(z);
          h4[j] = h;
          l4[j] = bf16rne(z - bf16tof(h));
        }
        size_t o = ((size_t)(b * T2) + t) * 512 + co;
        *(v4s*)&actOut[0 * (size_t)psOut + o] = h4;
        *(v4s*)&actOut[1 * (size_t)psOut + o] = l4;
      }
    }
}

// -------------------------------------------------------------------------
// conv_nl (MFMA) fused with the noise-bank filter.
// -------------------------------------------------------------------------
#define NL_PS4 8388608   // l4act plane stride (shorts)

__global__ void __launch_bounds__(128) conv_nl_filter(
    const short* __restrict__ act, const short* __restrict__ Pnl,
    const float* __restrict__ Bs, const float* __restrict__ noise,
    float* __restrict__ filt)
{
  const int bid = blockIdx.x;
  const int b = bid >> 4, t0 = (bid & 15) << 6;
  const int tid = threadIdx.x;
  const int w = tid >> 6;
  const int l = tid & 63;

  __shared__ __align__(16) short Al[2 * 3 * 32 * 72];
  __shared__ __align__(16) short Bl[2 * 66 * 72];
  __shared__ float magS[64][20];
  __shared__ float ctS[32], stS[32];

  if (tid < 32) {
    double a = (double)tid * (3.14159265358979323846 / 16.0);
    ctS[tid] = (float)cos(a);
    stS[tid] = (float)sin(a);
  }

  f32x16 acc = {};

  for (int ci0 = 0; ci0 < 512; ci0 += 64) {
    for (int e = tid; e < 1536; e += 128) {
      int c8 = e & 7, row = e >> 3;
      int pl = row >= 96;
      int r2 = row - pl * 96;
      int tap = r2 >> 5, co = r2 & 31;
      v8s vv = *(const v8s*)&Pnl[(size_t)(pl * 32 + co) * 1536 + tap * 512 + ci0 + c8 * 8];
      *(v8s*)&Al[row * 72 + c8 * 8] = vv;
    }
    for (int e = tid; e < 1056; e += 128) {
      int c8 = e & 7, r = (e >> 3) % 66, pl = (e >> 3) / 66;
      int t = t0 + r - 1;
      v8s vv = {};
      if (t >= 0 && t < 1024)
        vv = *(const v8s*)&act[(size_t)pl * NL_PS4 + ((size_t)(b << 10) + t) * 512 + ci0 + c8 * 8];
      *(v8s*)&Bl[(pl * 66 + r) * 72 + c8 * 8] = vv;
    }
    __syncthreads();
    const int lr = l & 31, lh = (l >> 5) * 8;
#pragma unroll
    for (int kk = 0; kk < 4; ++kk)
#pragma unroll
      for (int tap = 0; tap < 3; ++tap) {
        v8s a_h = *(const v8s*)&Al[((0 * 3 + tap) * 32 + lr) * 72 + kk * 16 + lh];
        v8s a_l = *(const v8s*)&Al[((1 * 3 + tap) * 32 + lr) * 72 + kk * 16 + lh];
        int brow = w * 32 + lr + tap;
        v8s b_h = *(const v8s*)&Bl[(0 * 66 + brow) * 72 + kk * 16 + lh];
        v8s b_l = *(const v8s*)&Bl[(1 * 66 + brow) * 72 + kk * 16 + lh];
        acc = __builtin_amdgcn_mfma_f32_32x32x16_bf16(a_h, b_h, acc, 0, 0, 0);
        acc = __builtin_amdgcn_mfma_f32_32x32x16_bf16(a_h, b_l, acc, 0, 0, 0);
        acc = __builtin_amdgcn_mfma_f32_32x32x16_bf16(a_l, b_h, acc, 0, 0, 0);
      }
    __syncthreads();
  }

  const int t_loc = w * 32 + (l & 31);
  const int hi4 = 4 * (l >> 5);
#pragma unroll
  for (int q4 = 0; q4 < 4; ++q4)
#pragma unroll
    for (int j = 0; j < 4; ++j) {
      int co = q4 * 8 + hi4 + j;
      if (co < 17) {
        float z = acc[q4 * 4 + j] + Bs[co];
        magS[t_loc][co] = z * z;
      }
    }
  __syncthreads();

  if (tid < 64) {
    int i = t0 + tid;
    float xv[32];
#pragma unroll
    for (int n = 0; n < 32; ++n) {
      int idx = i * 16 + n;
      xv[n] = (idx < 16384) ? noise[(size_t)b * 16384 + idx] : 0.f;
    }
    float Yr[17], Yi[17];
#pragma unroll
    for (int k = 0; k <= 16; ++k) {
      float xr = 0.f, xi = 0.f;
      int kk = 0;
#pragma unroll
      for (int n = 0; n < 32; ++n) {
        xr += xv[n] * ctS[kk];
        xi -= xv[n] * stS[kk];
        kk = (kk + k) & 31;
      }
      float m = magS[tid][k];
      Yr[k] = xr * m;
      Yi[k] = xi * m;
    }
    float* fo = filt + ((size_t)(b << 10) + i) * 32;
#pragma unroll
    for (int n = 0; n < 32; ++n) {
      float v = Yr[0] + ((n & 1) ? -Yr[16] : Yr[16]);
      int kk = n;
#pragma unroll
      for (int k = 1; k <= 15; ++k) {
        v += 2.f * (Yr[k] * ctS[kk] - Yi[k] * stS[kk]);
        kk = (kk + n) & 31;
      }
      fo[n] = v * (1.f / 32.f);
    }
  }
}

// -------------------------------------------------------------------------
// Oscillator bank (3-point lerp endpoints + f64 chunk base + f32 Kahan).
// -------------------------------------------------------------------------
static __device__ __forceinline__ int clamp64(int i) { return i < 0 ? 0 : (i > 63 ? 63 : i); }

__global__ void __launch_bounds__(256) osc_phase(
    const float* __restrict__ fsm, double* __restrict__ phaseBase)
{
  const int o = blockIdx.x, b = blockIdx.y;
  const float* frow = fsm + (size_t)(b * 128 + o) * 64;
  const int c = threadIdx.x;

  const float ic0 = ((float)(c * 64) - 127.5f) * (1.0f / 256.0f);
  const int ilo = (int)floorf(ic0);
  float f0 = frow[clamp64(ilo)], f1 = frow[clamp64(ilo + 1)], f2 = frow[clamp64(ilo + 2)];

  double local = 0.0;
#pragma unroll 8
  for (int j = 0; j < 64; ++j) {
    float ic = ic0 + (float)j * (1.0f / 256.0f);
    float fl = floorf(ic);
    float w  = ic - fl;
    bool hi = ((int)fl) > ilo;
    float fa = hi ? f1 : f0;
    float fb = hi ? f2 : f1;
    float f = fa * (1.f - w) + fb * w;
    f = fminf(fmaxf(f, 20.f), 11025.f);
    local += (double)f;
  }
  local *= (1.0 / 22050.0);

  __shared__ double ps[256];
  ps[c] = local;
  __syncthreads();
  for (int off = 1; off < 256; off <<= 1) {
    double v = (c >= off) ? ps[c - off] : 0.0;
    __syncthreads();
    ps[c] += v;
    __syncthreads();
  }
  phaseBase[(size_t)(b * 128 + o) * 256 + c] = ps[c] - local;
}

__global__ void __launch_bounds__(128) osc_sum(
    const float* __restrict__ fsm, const float* __restrict__ lsm,
    const double* __restrict__ phaseBase, const float* __restrict__ filt,
    float* __restrict__ out)
{
  const int c = blockIdx.x, b = blockIdx.y;
  const int tid = threadIdx.x;
  __shared__ float contrib[128][65];
  __shared__ float part[2][64];
  const int o = tid;
  const float* frow = fsm + (size_t)(b * 128 + o) * 64;
  const float* arow = lsm + (size_t)(b * 128 + o) * 64;

  double pb = phaseBase[(size_t)(b * 128 + o) * 256 + c];
  float fb0 = (float)(pb - floor(pb));

  const float ic0 = ((float)(c * 64) - 127.5f) * (1.0f / 256.0f);
  const int ilo = (int)floorf(ic0);
  float f0 = frow[clamp64(ilo)], f1 = frow[clamp64(ilo + 1)], f2 = frow[clamp64(ilo + 2)];
  float a0 = arow[clamp64(ilo)], a1 = arow[clamp64(ilo + 1)], a2 = arow[clamp64(ilo + 2)];

  float rel = 0.f, comp = 0.f;
#pragma unroll 8
  for (int j = 0; j < 64; ++j) {
    float ic = ic0 + (float)j * (1.0f / 256.0f);
    float fl = floorf(ic);
    float w  = ic - fl;
    bool hi = ((int)fl) > ilo;
    float fa = hi ? f1 : f0;
    float fb = hi ? f2 : f1;
    float f = fa * (1.f - w) + fb * w;
    f = fminf(fmaxf(f, 20.f), 11025.f);
    float y = f * (1.0f / 22050.0f) - comp;
    float t = rel + y;
    comp = (t - rel) - y;
    rel = t;
    float tot = fb0 + rel;
    float frac = tot - floorf(tot);
    float s = sinpif(2.f * frac);
    float aa = hi ? a1 : a0;
    float ab = hi ? a2 : a1;
    float am = aa * (1.f - w) + ab * w;
    contrib[o][j] = s * am;
  }
  __syncthreads();
  int half = tid >> 6, tl = tid & 63;
  float sum = 0.f;
  for (int oo = 0; oo < 64; ++oo) sum += contrib[half * 64 + oo][tl];
  part[half][tl] = sum;
  __syncthreads();
  if (tid < 64) {
    int t = c * 64 + tid;
    float v = part[0][tid] + part[1][tid];
    int i0 = t >> 4, r = t & 15;
    v += filt[((size_t)(b << 10) + i0) * 32 + r];
    if (i0 > 0) v += filt[((size_t)(b << 10) + i0 - 1) * 32 + 16 + r];
    out[(size_t)b * 16384 + t] = v;
  }
}

// -------------------------------------------------------------------------
extern "C" void kernel_launch(void* const* d_in, const int* in_sizes, int n_in,
                              void* d_out, int out_size, void* d_ws, size_t ws_size,
                              hipStream_t stream)
{
  (void)in_sizes; (void)n_in; (void)out_size; (void)ws_size;

  const float* x     = (const float*)d_in[0];
  const float* noise = (const float*)d_in[1];
  const float* mw0 = (const float*)d_in[2];  const float* mb0 = (const float*)d_in[3];
  const float* mw1 = (const float*)d_in[4];  const float* mb1 = (const float*)d_in[5];
  const float* mw2 = (const float*)d_in[6];  const float* mb2 = (const float*)d_in[7];
  const float* mw3 = (const float*)d_in[8];  const float* mb3 = (const float*)d_in[9];
  const float* fw  = (const float*)d_in[10]; const float* fb  = (const float*)d_in[11];
  const float* gw0 = (const float*)d_in[12]; const float* gb0 = (const float*)d_in[13];
  const float* gw1 = (const float*)d_in[14]; const float* gb1 = (const float*)d_in[15];
  const float* gw2 = (const float*)d_in[16]; const float* gb2 = (const float*)d_in[17];
  const float* gw3 = (const float*)d_in[18]; const float* gb3 = (const float*)d_in[19];
  const float* lw  = (const float*)d_in[20]; const float* lb  = (const float*)d_in[21];
  const float* nw0 = (const float*)d_in[22]; const float* nb0 = (const float*)d_in[23];
  const float* nw1 = (const float*)d_in[24]; const float* nb1 = (const float*)d_in[25];
  const float* nw2 = (const float*)d_in[26]; const float* nb2 = (const float*)d_in[27];
  const float* nw3 = (const float*)d_in[28]; const float* nb3 = (const float*)d_in[29];
  const float* nlw = (const float*)d_in[30]; const float* nlb = (const float*)d_in[31];

  // ---- workspace (BYTE offsets; same proven layout + liveness as round 10) ----
  char* W8 = (char*)d_ws;
  short* mP  = (short*)(W8 + 0);
  short* gP  = (short*)(W8 + 16515072);
  short* hm0 = (short*)(W8 + 33030144);
  short* hm1 = (short*)(W8 + 36175872);
  short* hg0 = (short*)(W8 + 39321600);
  short* hg1 = (short*)(W8 + 42467328);
  short* xm3 = (short*)(W8 + 58720256);
  float* fsm = (float*)(W8 + 59506688);
  float* lsm = (float*)(W8 + 60030976);
  short* Pnl = (short*)(W8 + 60555264);    // 196,608 B

  short* E4  = (short*)(W8 + 0);           // 8,388,608 B (over dead mP)
  short* E3  = (short*)(W8 + 33554432);    // 8,388,608 B
  short* E2  = (short*)(W8 + 41943040);    // 8,388,608 B
  short* E1  = (short*)(W8 + 50331648);    // 2,097,152 B
  short* l1out = (short*)(W8 + 52428800);  // 4,194,304 B
  short* l2out = (short*)(W8 + 25165824);  // 8,388,608 B
  short* l3out = (short*)(W8 + 8388608);   // 16,777,216 B
  short* l4act = (short*)(W8 + 25165824);  // 33,554,432 B

  float* filt = (float*)(W8 + 1114112);    // 2,097,152 B
  double* phaseBase = (double*)(W8 + 4194304);  // 4,194,304 B

  float* out = (float*)d_out;

  const int PS_X = 131072;   // xm3 plane stride (shorts)
  const int PS_H = 524288;   // m/g act plane stride (shorts)

  // ---- prep (acts + m/g panels only — noise panels alias live memory) ----
  prep_mg<<<1408, 256, 0, stream>>>(x, xm3,
      mw0, mw1, mw2, mw3, fw, gw0, gw1, gw2, gw3, lw, mP, gP);

  // ---- m/g paths: single kernel per layer (act + split fused) ----
  conv_path<<<256, 256, 0, stream>>>(xm3, xm3, mP + 0, gP + 0, mb0, gb0,
      nullptr, nullptr, hm0, hg0, 128, 512, PS_X, PS_H, ACT_LRELU, ACT_LRELU);
  conv_path<<<256, 256, 0, stream>>>(hm0, hg0, mP + 589824, gP + 589824, mb1, gb1,
      nullptr, nullptr, hm1, hg1, 512, 512, PS_H, PS_H, ACT_LRELU, ACT_LRELU);
  conv_path<<<256, 256, 0, stream>>>(hm1, hg1, mP + 2949120, gP + 2949120, mb2, gb2,
      nullptr, nullptr, hm0, hg0, 512, 512, PS_H, PS_H, ACT_LRELU, ACT_LRELU);
  conv_path<<<256, 256, 0, stream>>>(hm0, hg0, mP + 5308416, gP + 5308416, mb3, gb3,
      nullptr, nullptr, hm1, hg1, 512, 512, PS_H, PS_H, ACT_LRELU, ACT_LRELU);
  conv_path<<<64, 256, 0, stream>>>(hm1, hg1, mP + 7667712, gP + 7667712, fb, lb,
      fsm, lsm, nullptr, nullptr, 512, 128, PS_H, 0, ACT_SIGMAP, ACT_SQUARE);

  // ---- noise path (fold AFTER m/g chain: E-panels alias dead mP/hm/hg) ----
  fold_all<<<424, 256, 0, stream>>>(nw0, nw1, nw2, nw3, nlw, E1, E2, E3, E4, Pnl);
  conv_noise<1, 64, 128><<<256, 256, 0, stream>>>(xm3, E1, nb0, l1out, 64, PS_X, 1048576);
  conv_noise<2, 64, 512><<<256, 256, 0, stream>>>(l1out, E2, nb1, l2out, 128, 1048576, 2097152);
  conv_noise<2, 128, 512><<<256, 256, 0, stream>>>(l2out, E3, nb2, l3out, 256, 2097152, 4194304);
  conv_noise<2, 128, 512><<<512, 256, 0, stream>>>(l3out, E4, nb3, l4act, 512, 4194304, 8388608);

  // conv 512->17 + squared + per-frame DFT filter, fused
  conv_nl_filter<<<256, 128, 0, stream>>>(l4act, Pnl, nlb, noise, filt);

  // ---- oscillator bank + final sum ----
  osc_phase<<<dim3(128, 16), 256, 0, stream>>>(fsm, phaseBase);
  osc_sum<<<dim3(256, 16), 128, 0, stream>>>(fsm, lsm, phaseBase, filt, out);
}